// Round 6
// baseline (901.807 us; speedup 1.0000x reference)
//
#include <hip/hip_runtime.h>
#include <hip/hip_bf16.h>
#include <math.h>

// ---------------------------------------------------------------------------
// Full U-Mamba block. R6: conv d-split (grid x2 -> 4 waves/SIMD, no atomics);
// per-axis pipeline fused 4->2 kernels (dbc_k = conv1d+gemm_dbc via LDS;
// scanout_k = scan+gate+postLN+out-proj+accumulate, Ybuf eliminated).
// ---------------------------------------------------------------------------

typedef __attribute__((ext_vector_type(8))) short short8;   // 8 bf16 = 4 VGPR
typedef __attribute__((ext_vector_type(4))) float f32x4;

__device__ __forceinline__ float siluf(float x){ return x * (1.0f / (1.0f + __expf(-x))); }
__device__ __forceinline__ float softplusf(float x){ return fmaxf(x, 0.0f) + log1pf(__expf(-fabsf(x))); }
__device__ __forceinline__ float b2f(short s){
  unsigned int u = ((unsigned int)(unsigned short)s) << 16;
  float f; __builtin_memcpy(&f, &u, 4); return f;
}
__device__ __forceinline__ short f2b(float v){
  __hip_bfloat16 h = __float2bfloat16(v);
  unsigned short u; __builtin_memcpy(&u, &h, 2); return (short)u;
}

// ---------------------------------------------------------------------------
// One-shot setup: zero xpad | pack conv weights a/b -> bf16 [tap][co][ci] |
// mamba weight bf16 tables.
// ---------------------------------------------------------------------------
__global__ __launch_bounds__(256) void setup_k(uint4* __restrict__ xz,
    const float* __restrict__ cr1w, const float* __restrict__ cr2w,
    const float* __restrict__ lw, const float* __restrict__ rwt,
    const float* __restrict__ dwt, const float* __restrict__ bw,
    const float* __restrict__ cwp, const float* __restrict__ owt,
    __hip_bfloat16* __restrict__ W4a, __hip_bfloat16* __restrict__ W4b,
    __hip_bfloat16* __restrict__ Wlr, __hip_bfloat16* __restrict__ Wd,
    __hip_bfloat16* __restrict__ oWp)
{
  int i = blockIdx.x * 256 + threadIdx.x;
  if (i < 628864){ uint4 z; z.x = z.y = z.z = z.w = 0u; xz[i] = z; return; }
  i -= 628864;
  if (i < 110592){
    int tap = i >> 12, co = (i >> 6) & 63, ci = i & 63;
    W4a[i] = __float2bfloat16(cr1w[(co * 64 + ci) * 27 + tap]); return;
  }
  i -= 110592;
  if (i < 110592){
    int tap = i >> 12, co = (i >> 6) & 63, ci = i & 63;
    W4b[i] = __float2bfloat16(cr2w[(co * 64 + ci) * 27 + tap]); return;
  }
  i -= 110592;
  if (i < 16384){
    int row = i >> 6, c = i & 63;
    float v = (row < 128) ? lw[row * 64 + c] : rwt[(row - 128) * 64 + c];
    Wlr[i] = __float2bfloat16(v); return;
  }
  i -= 16384;
  if (i < 20480){
    int row = i >> 7, k = i & 127;
    float v = (row < 128) ? dwt[row * 128 + k]
            : (row < 144 ? bw[(row - 128) * 128 + k] : cwp[(row - 144) * 128 + k]);
    Wd[i] = __float2bfloat16(v); return;
  }
  i -= 20480;
  if (i < 8192){ oWp[i] = __float2bfloat16(owt[i]); return; }
}

// ---------------------------------------------------------------------------
// Pack fp32 NCDHW -> padded channels-last bf16 [b][h+1][w+1][d+1][c] (conv1).
// ---------------------------------------------------------------------------
__global__ __launch_bounds__(256) void pack_k(const float* __restrict__ xin,
                                              __hip_bfloat16* __restrict__ xpad)
{
  __shared__ float lds[64 * 33];
  const int t = threadIdx.x, blk = blockIdx.x;
  const int b = blk >> 10, h = (blk >> 5) & 31, w = blk & 31;
  const size_t rbase = ((size_t)(b * 64) << 15) + h * 1024 + w * 32;
  #pragma unroll
  for (int r = 0; r < 8; r++){
    int c = r * 8 + (t >> 5), d = t & 31;
    lds[c * 33 + d] = xin[rbase + (size_t)c * 32768 + d];
  }
  __syncthreads();
  const size_t wbase = (size_t)b * 2515456 + (size_t)(h + 1) * 73984 + (w + 1) * 2176 + 64;
  #pragma unroll
  for (int r = 0; r < 8; r++){
    int d = r * 4 + (t >> 6), c = t & 63;
    xpad[wbase + d * 64 + c] = __float2bfloat16(lds[c * 33 + d]);
  }
}

// ---------------------------------------------------------------------------
// Conv3d implicit GEMM, bf16 MFMA 16x16x32. R6: d-split -> grid
// (256 tiles, 2 d-halves, 2 b) = 1024 blocks = 4 waves/SIMD. Per wave:
// 64co x 1w x 16d; 1 B-frag + 4 A-frags (A block-uniform -> L1-hot),
// 4 MFMAs/step; flattened 54-step K-loop with depth-1 register prefetch.
// Bias canceled by InstanceNorm and dropped.
// ---------------------------------------------------------------------------
__global__ __launch_bounds__(256) void conv_mfma_k(const __hip_bfloat16* __restrict__ xpad,
    const __hip_bfloat16* __restrict__ W4, float* __restrict__ y)
{
  const int t = threadIdx.x;
  const int wave = t >> 6, lane = t & 63;
  const int quad = lane >> 4, ln = lane & 15;
  const int tile = blockIdx.x, dh = blockIdx.y, b = blockIdx.z;
  const int h = tile >> 3, w0 = (tile & 7) * 4;

  f32x4 acc[4];
  #pragma unroll
  for (int m = 0; m < 4; m++) acc[m] = (f32x4){0.f, 0.f, 0.f, 0.f};

  const size_t ib = (size_t)b * 2515456 + (size_t)h * 73984 + (size_t)(w0 + wave) * 2176
                    + (size_t)dh * 1024 + (size_t)ln * 64 + quad * 8;
  const int wbase = ln * 64 + quad * 8;

  short8 cb, ca0, ca1, ca2, ca3;
  cb  = *(const short8*)(xpad + ib);
  ca0 = *(const short8*)(W4 + wbase);
  ca1 = *(const short8*)(W4 + wbase + 1024);
  ca2 = *(const short8*)(W4 + wbase + 2048);
  ca3 = *(const short8*)(W4 + wbase + 3072);

  #pragma unroll
  for (int s = 0; s < 54; s++){
    short8 nb, na0, na1, na2, na3;
    if (s + 1 < 54){
      const int t1 = (s + 1) >> 1, c1 = (s + 1) & 1;
      const int ki = t1 / 9, kj = (t1 / 3) % 3, kk = t1 % 3;
      const int o  = ki * 73984 + kj * 2176 + kk * 64 + c1 * 32;
      const int wo = t1 * 4096 + c1 * 32 + wbase;
      nb  = *(const short8*)(xpad + ib + o);
      na0 = *(const short8*)(W4 + wo);
      na1 = *(const short8*)(W4 + wo + 1024);
      na2 = *(const short8*)(W4 + wo + 2048);
      na3 = *(const short8*)(W4 + wo + 3072);
    }
    acc[0] = __builtin_amdgcn_mfma_f32_16x16x32_bf16(ca0, cb, acc[0], 0, 0, 0);
    acc[1] = __builtin_amdgcn_mfma_f32_16x16x32_bf16(ca1, cb, acc[1], 0, 0, 0);
    acc[2] = __builtin_amdgcn_mfma_f32_16x16x32_bf16(ca2, cb, acc[2], 0, 0, 0);
    acc[3] = __builtin_amdgcn_mfma_f32_16x16x32_bf16(ca3, cb, acc[3], 0, 0, 0);
    cb = nb; ca0 = na0; ca1 = na1; ca2 = na2; ca3 = na3;
  }

  const size_t sbase = (size_t)h * 1024 + (w0 + wave) * 32 + dh * 16 + ln;
  #pragma unroll
  for (int mt = 0; mt < 4; mt++){
    #pragma unroll
    for (int reg = 0; reg < 4; reg++){
      int co = mt * 16 + quad * 4 + reg;
      y[(((size_t)(b * 64 + co)) << 15) + sbase] = acc[mt][reg];
    }
  }
}

// ---------------------------------------------------------------------------
// InstanceNorm3d stats: one block per (b,c); stats[g]=mu, stats[128+g]=rsigma.
// ---------------------------------------------------------------------------
__global__ __launch_bounds__(256) void inorm_stats_k(const float* __restrict__ y,
                                                     float* __restrict__ stats)
{
  __shared__ float ss[256], ss2[256];
  const int t = threadIdx.x, g = blockIdx.x;
  const float* p = y + (size_t)g * 32768;
  float s = 0.0f, s2 = 0.0f;
  for (int i = t; i < 32768; i += 256){ float v = p[i]; s += v; s2 += v * v; }
  ss[t] = s; ss2[t] = s2;
  __syncthreads();
  for (int off = 128; off > 0; off >>= 1){
    if (t < off){ ss[t] += ss[t + off]; ss2[t] += ss2[t + off]; }
    __syncthreads();
  }
  if (t == 0){
    float mu = ss[0] * (1.0f / 32768.0f);
    float var = ss2[0] * (1.0f / 32768.0f) - mu * mu;
    stats[g] = mu;
    stats[128 + g] = rsqrtf(var + 1e-5f);
  }
}

// ---------------------------------------------------------------------------
// Fused: InstanceNorm-apply + LeakyReLU + residual -> x1 (fp32 NCDHW)
// AND bf16 channels-last re-pack into xpad (input of conv2).
// ---------------------------------------------------------------------------
__global__ __launch_bounds__(256) void apply_pack_k(const float* __restrict__ xin,
    const float* __restrict__ y, const float* __restrict__ stats,
    float* __restrict__ x1, __hip_bfloat16* __restrict__ xpad)
{
  __shared__ float lds[64 * 33];
  const int t = threadIdx.x, blk = blockIdx.x;
  const int b = blk >> 10, h = (blk >> 5) & 31, w = blk & 31;
  const size_t rbase = ((size_t)(b * 64) << 15) + h * 1024 + w * 32;
  #pragma unroll
  for (int r = 0; r < 8; r++){
    int c = r * 8 + (t >> 5), d = t & 31;
    float mu = stats[b * 64 + c], rs = stats[128 + b * 64 + c];
    float v = (y[rbase + (size_t)c * 32768 + d] - mu) * rs;
    v = (v >= 0.0f) ? v : 0.01f * v;
    v += xin[rbase + (size_t)c * 32768 + d];
    x1[rbase + (size_t)c * 32768 + d] = v;
    lds[c * 33 + d] = v;
  }
  __syncthreads();
  const size_t wbase = (size_t)b * 2515456 + (size_t)(h + 1) * 73984 + (w + 1) * 2176 + 64;
  #pragma unroll
  for (int r = 0; r < 8; r++){
    int d = r * 4 + (t >> 6), c = t & 63;
    xpad[wbase + d * 64 + c] = __float2bfloat16(lds[c * 33 + d]);
  }
}

// ---------------------------------------------------------------------------
// Fused: InstanceNorm-apply + LeakyReLU + residual + LayerNorm over C
// -> bf16 channels-last lnx [pos][64]. x2 never materialized.
// ---------------------------------------------------------------------------
__global__ __launch_bounds__(256) void apply_ln_k(const float* __restrict__ x1,
    const float* __restrict__ y, const float* __restrict__ stats,
    const float* __restrict__ lnw, const float* __restrict__ lnb,
    __hip_bfloat16* __restrict__ lnx)
{
  __shared__ float lds[64 * 33];
  __shared__ float s_mu[32], s_rs[32];
  const int t = threadIdx.x, blk = blockIdx.x;
  const int b = blk >> 10, h = (blk >> 5) & 31, w = blk & 31;
  const size_t rbase = ((size_t)(b * 64) << 15) + h * 1024 + w * 32;
  #pragma unroll
  for (int r = 0; r < 8; r++){
    int c = r * 8 + (t >> 5), d = t & 31;
    float mu = stats[b * 64 + c], rs = stats[128 + b * 64 + c];
    float v = (y[rbase + (size_t)c * 32768 + d] - mu) * rs;
    v = (v >= 0.0f) ? v : 0.01f * v;
    lds[c * 33 + d] = v + x1[rbase + (size_t)c * 32768 + d];
  }
  __syncthreads();
  if (t < 32){
    float s = 0.f, s2 = 0.f;
    for (int c = 0; c < 64; c++){ float v = lds[c * 33 + t]; s += v; s2 += v * v; }
    float mu = s * (1.f / 64.f);
    float var = s2 * (1.f / 64.f) - mu * mu;
    s_mu[t] = mu; s_rs[t] = rsqrtf(var + 1e-5f);
  }
  __syncthreads();
  const int d = t >> 3, c0 = (t & 7) * 8;
  const int pos = b * 32768 + h * 1024 + w * 32 + d;
  const float mu = s_mu[d], rs = s_rs[d];
  short8 o;
  #pragma unroll
  for (int j = 0; j < 8; j++){
    int c = c0 + j;
    o[j] = f2b((lds[c * 33 + d] - mu) * rs * lnw[c] + lnb[c]);
  }
  *(short8*)&lnx[(size_t)pos * 64 + c0] = o;
}

// ---------------------------------------------------------------------------
// GEMM [65536,64] x [64,256] -> Lbuf (cols 0-127 raw) + Gbuf (silu, 128-255).
// ---------------------------------------------------------------------------
__global__ __launch_bounds__(256) void gemm_lr_k(const __hip_bfloat16* __restrict__ lnx,
    const __hip_bfloat16* __restrict__ Wlr, __hip_bfloat16* __restrict__ Lb,
    __hip_bfloat16* __restrict__ Gb)
{
  const int t = threadIdx.x, wave = t >> 6, lane = t & 63, quad = lane >> 4, ln = lane & 15;
  const int pos0 = blockIdx.x * 64 + wave * 16;
  f32x4 acc[16];
  #pragma unroll
  for (int nt = 0; nt < 16; nt++) acc[nt] = (f32x4){0.f, 0.f, 0.f, 0.f};
  #pragma unroll
  for (int ks = 0; ks < 2; ks++){
    short8 a = *(const short8*)&lnx[(size_t)(pos0 + ln) * 64 + ks * 32 + quad * 8];
    #pragma unroll
    for (int nt = 0; nt < 16; nt++){
      short8 bv = *(const short8*)&Wlr[(nt * 16 + ln) * 64 + ks * 32 + quad * 8];
      acc[nt] = __builtin_amdgcn_mfma_f32_16x16x32_bf16(a, bv, acc[nt], 0, 0, 0);
    }
  }
  #pragma unroll
  for (int nt = 0; nt < 16; nt++){
    int col = nt * 16 + ln;
    #pragma unroll
    for (int reg = 0; reg < 4; reg++){
      int pos = pos0 + quad * 4 + reg;
      float v = acc[nt][reg];
      if (col < 128) Lb[(size_t)pos * 128 + col] = __float2bfloat16(v);
      else           Gb[(size_t)pos * 128 + col - 128] = __float2bfloat16(siluf(v));
    }
  }
}

// ---------------------------------------------------------------------------
// FUSED per-axis: conv1d(k=4)+silu -> LDS tile -> GEMM [64,128]x[128,160].
// Block: 64 positions, 256 thr. Phase 1: each thread computes 4x(1 pos,8 ch)
// conv results, writes bf16 to LDS tile (stride 136) + global xl.
// Phase 2: wave w = pos-tile (16 pos); A-frags from LDS, B=Wd (L2-hot);
// 10 n-tiles x 4 k-steps MFMA. cols 0-127 delta(softplus/clip), 128+: B/C.
// ---------------------------------------------------------------------------
__global__ __launch_bounds__(256) void dbc_k(const __hip_bfloat16* __restrict__ Lb,
    const float* __restrict__ cw, const float* __restrict__ cb,
    const __hip_bfloat16* __restrict__ Wd, const float* __restrict__ db,
    __hip_bfloat16* __restrict__ xl, __hip_bfloat16* __restrict__ dbc, int sh)
{
  __shared__ short s_xl[64 * 136];
  const int t = threadIdx.x;
  const int pos0 = blockIdx.x * 64;
  const int sigma = 1 << sh;

  #pragma unroll
  for (int r = 0; r < 4; r++){
    int i = t + r * 256;
    int pi = i >> 4, c0 = (i & 15) * 8;
    int pos = pos0 + pi;
    int l = (pos >> sh) & 31;
    float acc[8]; float4 w4[8];
    #pragma unroll
    for (int c = 0; c < 8; c++){ w4[c] = *(const float4*)&cw[(c0 + c) * 4]; acc[c] = cb[c0 + c]; }
    #pragma unroll
    for (int j = 0; j < 4; j++){
      int off = 3 - j;
      if (l >= off){
        short8 lv = *(const short8*)&Lb[(size_t)(pos - off * sigma) * 128 + c0];
        #pragma unroll
        for (int c = 0; c < 8; c++){
          float wv = (j == 0) ? w4[c].x : (j == 1) ? w4[c].y : (j == 2) ? w4[c].z : w4[c].w;
          acc[c] += wv * b2f(lv[c]);
        }
      }
    }
    short8 o;
    #pragma unroll
    for (int c = 0; c < 8; c++) o[c] = f2b(siluf(acc[c]));
    *(short8*)&s_xl[pi * 136 + c0] = o;
    *(short8*)&xl[(size_t)pos * 128 + c0] = o;
  }
  __syncthreads();

  const int wave = t >> 6, lane = t & 63, quad = lane >> 4, ln = lane & 15;
  const int rowb = (wave * 16 + ln) * 136;
  f32x4 acc2[10];
  #pragma unroll
  for (int nt = 0; nt < 10; nt++) acc2[nt] = (f32x4){0.f, 0.f, 0.f, 0.f};
  #pragma unroll
  for (int ks = 0; ks < 4; ks++){
    short8 a = *(const short8*)&s_xl[rowb + ks * 32 + quad * 8];
    #pragma unroll
    for (int nt = 0; nt < 10; nt++){
      short8 bv = *(const short8*)&Wd[(nt * 16 + ln) * 128 + ks * 32 + quad * 8];
      acc2[nt] = __builtin_amdgcn_mfma_f32_16x16x32_bf16(a, bv, acc2[nt], 0, 0, 0);
    }
  }
  const int posw = pos0 + wave * 16 + quad * 4;
  #pragma unroll
  for (int nt = 0; nt < 10; nt++){
    int col = nt * 16 + ln;
    bool isd = col < 128;
    float dbv = isd ? db[col] : 0.f;
    #pragma unroll
    for (int reg = 0; reg < 4; reg++){
      float v = acc2[nt][reg];
      if (isd) v = fminf(fmaxf(softplusf(v + dbv), 1e-4f), 10.f);
      dbc[(size_t)(posw + reg) * 160 + col] = __float2bfloat16(v);
    }
  }
}

// ---------------------------------------------------------------------------
// FUSED per-axis: selective scan + gate + post-LN (in LDS, f32) + out-proj
// MFMA + softmax(axis_w)-weighted accumulate into d_out.
// 1 block (128 thr = 2 waves) per sequence. mode: 0=store,1=add,2=finalize.
// ---------------------------------------------------------------------------
__global__ __launch_bounds__(128) void scanout_k(const __hip_bfloat16* __restrict__ dbc,
    const __hip_bfloat16* __restrict__ xl, const __hip_bfloat16* __restrict__ Gb,
    const float* __restrict__ alog, const float* __restrict__ pnw, const float* __restrict__ pnb,
    const __hip_bfloat16* __restrict__ oW, const float* __restrict__ axw,
    const float* __restrict__ xres, const float* __restrict__ rsc,
    float* __restrict__ outp, int axis, int mode)
{
  __shared__ float s_B[512], s_C[512], s_y[32 * 132], s_mu[32], s_rs[32];
  const int t = threadIdx.x, seq = blockIdx.x;
  const int b = seq >> 10, r1 = (seq >> 5) & 31, r0 = seq & 31;
  int basehw, sigma;
  if (axis == 0){      basehw = r1 * 32 + r0;        sigma = 1024; }
  else if (axis == 1){ basehw = r1 * 1024 + r0;      sigma = 32; }
  else {               basehw = r1 * 1024 + r0 * 32; sigma = 1; }
  const int base = b * 32768 + basehw;

  for (int i = t; i < 1024; i += 128){
    int l = i >> 5, j = i & 31;
    float v = __bfloat162float(dbc[(size_t)(base + l * sigma) * 160 + 128 + j]);
    if (j < 16) s_B[l * 16 + j] = v; else s_C[l * 16 + (j - 16)] = v;
  }
  float A[16], h[16];
  #pragma unroll
  for (int s = 0; s < 16; s++){ A[s] = -softplusf(alog[s]); h[s] = 0.f; }
  __syncthreads();

  const int d = t;
  for (int l = 0; l < 32; l++){
    size_t row = (size_t)(base + l * sigma);
    float dt = __bfloat162float(dbc[row * 160 + d]);
    float xt = __bfloat162float(xl[row * 128 + d]);
    float g  = __bfloat162float(Gb[row * 128 + d]);
    float dx = dt * xt, yv = 0.f;
    #pragma unroll
    for (int s = 0; s < 16; s++){
      h[s] = __expf(dt * A[s]) * h[s] + dx * s_B[l * 16 + s];
      yv += h[s] * s_C[l * 16 + s];
    }
    s_y[l * 132 + d] = yv * g;
  }
  __syncthreads();
  if (t < 32){
    float s = 0.f, s2 = 0.f;
    for (int k = 0; k < 128; k++){ float v = s_y[t * 132 + k]; s += v; s2 += v * v; }
    float mu = s * (1.f / 128.f), var = s2 * (1.f / 128.f) - mu * mu;
    s_mu[t] = mu; s_rs[t] = rsqrtf(var + 1e-5f);
  }
  __syncthreads();
  const float pw = pnw[d], pb = pnb[d];
  for (int l = 0; l < 32; l++)
    s_y[l * 132 + d] = (s_y[l * 132 + d] - s_mu[l]) * s_rs[l] * pw + pb;
  __syncthreads();

  // out-projection: wave wv owns pos-tile (16 seq positions)
  const int wv = t >> 6, lane = t & 63, quad = lane >> 4, ln = lane & 15;
  f32x4 acc[4];
  #pragma unroll
  for (int mt = 0; mt < 4; mt++) acc[mt] = (f32x4){0.f, 0.f, 0.f, 0.f};
  #pragma unroll
  for (int ks = 0; ks < 4; ks++){
    const float* yr = &s_y[(wv * 16 + ln) * 132 + ks * 32 + quad * 8];
    short8 bv;
    #pragma unroll
    for (int j = 0; j < 8; j++) bv[j] = f2b(yr[j]);
    #pragma unroll
    for (int mt = 0; mt < 4; mt++){
      short8 a = *(const short8*)&oW[(mt * 16 + ln) * 128 + ks * 32 + quad * 8];
      acc[mt] = __builtin_amdgcn_mfma_f32_16x16x32_bf16(a, bv, acc[mt], 0, 0, 0);
    }
  }
  float a0 = axw[0], a1 = axw[1], a2 = axw[2];
  float mx = fmaxf(a0, fmaxf(a1, a2));
  float e0 = __expf(a0 - mx), e1 = __expf(a1 - mx), e2 = __expf(a2 - mx);
  float wax = ((axis == 0) ? e0 : (axis == 1) ? e1 : e2) / (e0 + e1 + e2);
  float rs = rsc[0];
  const int l = wv * 16 + ln;                   // D col = seq position
  const size_t hwoff = (size_t)basehw + (size_t)l * sigma;
  #pragma unroll
  for (int mt = 0; mt < 4; mt++){
    #pragma unroll
    for (int reg = 0; reg < 4; reg++){
      int co = mt * 16 + quad * 4 + reg;
      size_t idx = (((size_t)(b * 64 + co)) << 15) + hwoff;
      float v = acc[mt][reg] * wax;
      if (mode == 0)      outp[idx] = v;
      else if (mode == 1) outp[idx] += v;
      else                outp[idx] = xres[idx] + rs * (outp[idx] + v);
    }
  }
}

// ---------------------------------------------------------------------------
extern "C" void kernel_launch(void* const* d_in, const int* in_sizes, int n_in,
                              void* d_out, int out_size, void* d_ws, size_t ws_size,
                              hipStream_t stream)
{
  const float* x      = (const float*)d_in[0];
  const float* cr1w   = (const float*)d_in[1];
  const float* cr2w   = (const float*)d_in[3];
  const float* ln_w   = (const float*)d_in[5];
  const float* ln_b   = (const float*)d_in[6];
  const float* left_w = (const float*)d_in[7];
  const float* c1dw   = (const float*)d_in[8];
  const float* c1db   = (const float*)d_in[9];
  const float* dw     = (const float*)d_in[10];
  const float* db     = (const float*)d_in[11];
  const float* bpw    = (const float*)d_in[12];
  const float* cpw    = (const float*)d_in[13];
  const float* alog   = (const float*)d_in[14];
  const float* rw     = (const float*)d_in[15];
  const float* pnw    = (const float*)d_in[16];
  const float* pnb    = (const float*)d_in[17];
  const float* ow     = (const float*)d_in[18];
  const float* rsc    = (const float*)d_in[19];
  const float* axw    = (const float*)d_in[20];
  float* out = (float*)d_out;                       // conv raw out, then mamba accum
  float* wsf = (float*)d_ws;

  float* buf1   = wsf;                                         // x1 fp32; later xl bf16 alias
  float* stats  = wsf + 4194304;                               // 256 f
  __hip_bfloat16* W4a  = (__hip_bfloat16*)(wsf + 4194816);     // 110,592 bf16
  __hip_bfloat16* W4b  = W4a + 110592;
  __hip_bfloat16* Wlr  = (__hip_bfloat16*)(wsf + 4305408);     // 16,384 bf16
  __hip_bfloat16* Wdbc = (__hip_bfloat16*)(wsf + 4313600);     // 20,480 bf16
  __hip_bfloat16* oWp  = (__hip_bfloat16*)(wsf + 4323840);     // 8,192 bf16
  __hip_bfloat16* xpad = (__hip_bfloat16*)(wsf + 4327936);     // 5,030,912 bf16
  __hip_bfloat16* lnx  = xpad;                                 // alias (post-conv)
  __hip_bfloat16* Lbuf = (__hip_bfloat16*)(wsf + 6843392);     // 8,388,608 bf16
  __hip_bfloat16* Gbuf = (__hip_bfloat16*)(wsf + 11037696);    // 8,388,608 bf16
  __hip_bfloat16* dbc  = (__hip_bfloat16*)(wsf + 15232000);    // 10,485,760 bf16
  __hip_bfloat16* xl   = (__hip_bfloat16*)buf1;                // alias (x1 dead after apply_ln)

  setup_k<<<3497, 256, 0, stream>>>((uint4*)xpad, cr1w, cr2w, left_w, rw, dw, bpw, cpw, ow,
                                    W4a, W4b, Wlr, Wdbc, oWp);

  dim3 cgrid(256, 2, 2);
  // conv-res block 1
  pack_k<<<2048, 256, 0, stream>>>(x, xpad);
  conv_mfma_k<<<cgrid, 256, 0, stream>>>(xpad, W4a, out);
  inorm_stats_k<<<128, 256, 0, stream>>>(out, stats);
  apply_pack_k<<<2048, 256, 0, stream>>>(x, out, stats, buf1, xpad);
  // conv-res block 2 (fused apply + LayerNorm; x2 never materialized)
  conv_mfma_k<<<cgrid, 256, 0, stream>>>(xpad, W4b, out);
  inorm_stats_k<<<128, 256, 0, stream>>>(out, stats);
  apply_ln_k<<<2048, 256, 0, stream>>>(buf1, out, stats, ln_w, ln_b, lnx);

  // mamba: axis-independent projection once
  gemm_lr_k<<<1024, 256, 0, stream>>>(lnx, Wlr, Lbuf, Gbuf);

  // per-axis fused pipeline: dbc_k (conv1d+gemm) -> scanout_k (scan+out-proj)
  const int sh[3] = {10, 5, 0};
  for (int axis = 0; axis < 3; axis++){
    dbc_k<<<1024, 256, 0, stream>>>(Lbuf, c1dw, c1db, Wdbc, db, xl, dbc, sh[axis]);
    scanout_k<<<2048, 128, 0, stream>>>(dbc, xl, Gbuf, alog, pnw, pnb, oWp, axw,
                                        x, rsc, out, axis,
                                        axis == 0 ? 0 : (axis == 2 ? 2 : 1));
  }
}

// Round 7
// 854.444 us; speedup vs baseline: 1.0554x; 1.0554x over previous
//
#include <hip/hip_runtime.h>
#include <hip/hip_bf16.h>
#include <math.h>

// ---------------------------------------------------------------------------
// Full U-Mamba block. R7: revert R6's scanout fusion (per-sequence out-proj
// stores can't coalesce for axes 0/1 -> 16x write amplification, 300MB/disp).
// scan_k writes pos-major Ybuf; gemm_out_k does coalesced accumulate.
// Keep: R6 d-split conv, fused dbc_k, all glue fusions.
// ---------------------------------------------------------------------------

typedef __attribute__((ext_vector_type(8))) short short8;   // 8 bf16 = 4 VGPR
typedef __attribute__((ext_vector_type(4))) float f32x4;

__device__ __forceinline__ float siluf(float x){ return x * (1.0f / (1.0f + __expf(-x))); }
__device__ __forceinline__ float softplusf(float x){ return fmaxf(x, 0.0f) + log1pf(__expf(-fabsf(x))); }
__device__ __forceinline__ float b2f(short s){
  unsigned int u = ((unsigned int)(unsigned short)s) << 16;
  float f; __builtin_memcpy(&f, &u, 4); return f;
}
__device__ __forceinline__ short f2b(float v){
  __hip_bfloat16 h = __float2bfloat16(v);
  unsigned short u; __builtin_memcpy(&u, &h, 2); return (short)u;
}

// ---------------------------------------------------------------------------
// One-shot setup: zero xpad | pack conv weights a/b -> bf16 [tap][co][ci] |
// mamba weight bf16 tables.
// ---------------------------------------------------------------------------
__global__ __launch_bounds__(256) void setup_k(uint4* __restrict__ xz,
    const float* __restrict__ cr1w, const float* __restrict__ cr2w,
    const float* __restrict__ lw, const float* __restrict__ rwt,
    const float* __restrict__ dwt, const float* __restrict__ bw,
    const float* __restrict__ cwp, const float* __restrict__ owt,
    __hip_bfloat16* __restrict__ W4a, __hip_bfloat16* __restrict__ W4b,
    __hip_bfloat16* __restrict__ Wlr, __hip_bfloat16* __restrict__ Wd,
    __hip_bfloat16* __restrict__ oWp)
{
  int i = blockIdx.x * 256 + threadIdx.x;
  if (i < 628864){ uint4 z; z.x = z.y = z.z = z.w = 0u; xz[i] = z; return; }
  i -= 628864;
  if (i < 110592){
    int tap = i >> 12, co = (i >> 6) & 63, ci = i & 63;
    W4a[i] = __float2bfloat16(cr1w[(co * 64 + ci) * 27 + tap]); return;
  }
  i -= 110592;
  if (i < 110592){
    int tap = i >> 12, co = (i >> 6) & 63, ci = i & 63;
    W4b[i] = __float2bfloat16(cr2w[(co * 64 + ci) * 27 + tap]); return;
  }
  i -= 110592;
  if (i < 16384){
    int row = i >> 6, c = i & 63;
    float v = (row < 128) ? lw[row * 64 + c] : rwt[(row - 128) * 64 + c];
    Wlr[i] = __float2bfloat16(v); return;
  }
  i -= 16384;
  if (i < 20480){
    int row = i >> 7, k = i & 127;
    float v = (row < 128) ? dwt[row * 128 + k]
            : (row < 144 ? bw[(row - 128) * 128 + k] : cwp[(row - 144) * 128 + k]);
    Wd[i] = __float2bfloat16(v); return;
  }
  i -= 20480;
  if (i < 8192){ oWp[i] = __float2bfloat16(owt[i]); return; }
}

// ---------------------------------------------------------------------------
// Pack fp32 NCDHW -> padded channels-last bf16 [b][h+1][w+1][d+1][c] (conv1).
// ---------------------------------------------------------------------------
__global__ __launch_bounds__(256) void pack_k(const float* __restrict__ xin,
                                              __hip_bfloat16* __restrict__ xpad)
{
  __shared__ float lds[64 * 33];
  const int t = threadIdx.x, blk = blockIdx.x;
  const int b = blk >> 10, h = (blk >> 5) & 31, w = blk & 31;
  const size_t rbase = ((size_t)(b * 64) << 15) + h * 1024 + w * 32;
  #pragma unroll
  for (int r = 0; r < 8; r++){
    int c = r * 8 + (t >> 5), d = t & 31;
    lds[c * 33 + d] = xin[rbase + (size_t)c * 32768 + d];
  }
  __syncthreads();
  const size_t wbase = (size_t)b * 2515456 + (size_t)(h + 1) * 73984 + (w + 1) * 2176 + 64;
  #pragma unroll
  for (int r = 0; r < 8; r++){
    int d = r * 4 + (t >> 6), c = t & 63;
    xpad[wbase + d * 64 + c] = __float2bfloat16(lds[c * 33 + d]);
  }
}

// ---------------------------------------------------------------------------
// Conv3d implicit GEMM, bf16 MFMA 16x16x32. d-split grid (256,2,2) = 1024
// blocks = 4 waves/SIMD. Per wave: 64co x 1w x 16d; 1 B-frag + 4 A-frags
// (A block-uniform -> L1-hot); flattened 54-step K-loop, depth-1 prefetch.
// Bias canceled by InstanceNorm and dropped.
// ---------------------------------------------------------------------------
__global__ __launch_bounds__(256) void conv_mfma_k(const __hip_bfloat16* __restrict__ xpad,
    const __hip_bfloat16* __restrict__ W4, float* __restrict__ y)
{
  const int t = threadIdx.x;
  const int wave = t >> 6, lane = t & 63;
  const int quad = lane >> 4, ln = lane & 15;
  const int tile = blockIdx.x, dh = blockIdx.y, b = blockIdx.z;
  const int h = tile >> 3, w0 = (tile & 7) * 4;

  f32x4 acc[4];
  #pragma unroll
  for (int m = 0; m < 4; m++) acc[m] = (f32x4){0.f, 0.f, 0.f, 0.f};

  const size_t ib = (size_t)b * 2515456 + (size_t)h * 73984 + (size_t)(w0 + wave) * 2176
                    + (size_t)dh * 1024 + (size_t)ln * 64 + quad * 8;
  const int wbase = ln * 64 + quad * 8;

  short8 cb, ca0, ca1, ca2, ca3;
  cb  = *(const short8*)(xpad + ib);
  ca0 = *(const short8*)(W4 + wbase);
  ca1 = *(const short8*)(W4 + wbase + 1024);
  ca2 = *(const short8*)(W4 + wbase + 2048);
  ca3 = *(const short8*)(W4 + wbase + 3072);

  #pragma unroll
  for (int s = 0; s < 54; s++){
    short8 nb, na0, na1, na2, na3;
    if (s + 1 < 54){
      const int t1 = (s + 1) >> 1, c1 = (s + 1) & 1;
      const int ki = t1 / 9, kj = (t1 / 3) % 3, kk = t1 % 3;
      const int o  = ki * 73984 + kj * 2176 + kk * 64 + c1 * 32;
      const int wo = t1 * 4096 + c1 * 32 + wbase;
      nb  = *(const short8*)(xpad + ib + o);
      na0 = *(const short8*)(W4 + wo);
      na1 = *(const short8*)(W4 + wo + 1024);
      na2 = *(const short8*)(W4 + wo + 2048);
      na3 = *(const short8*)(W4 + wo + 3072);
    }
    acc[0] = __builtin_amdgcn_mfma_f32_16x16x32_bf16(ca0, cb, acc[0], 0, 0, 0);
    acc[1] = __builtin_amdgcn_mfma_f32_16x16x32_bf16(ca1, cb, acc[1], 0, 0, 0);
    acc[2] = __builtin_amdgcn_mfma_f32_16x16x32_bf16(ca2, cb, acc[2], 0, 0, 0);
    acc[3] = __builtin_amdgcn_mfma_f32_16x16x32_bf16(ca3, cb, acc[3], 0, 0, 0);
    cb = nb; ca0 = na0; ca1 = na1; ca2 = na2; ca3 = na3;
  }

  const size_t sbase = (size_t)h * 1024 + (w0 + wave) * 32 + dh * 16 + ln;
  #pragma unroll
  for (int mt = 0; mt < 4; mt++){
    #pragma unroll
    for (int reg = 0; reg < 4; reg++){
      int co = mt * 16 + quad * 4 + reg;
      y[(((size_t)(b * 64 + co)) << 15) + sbase] = acc[mt][reg];
    }
  }
}

// ---------------------------------------------------------------------------
// InstanceNorm3d stats: one block per (b,c); stats[g]=mu, stats[128+g]=rsigma.
// ---------------------------------------------------------------------------
__global__ __launch_bounds__(256) void inorm_stats_k(const float* __restrict__ y,
                                                     float* __restrict__ stats)
{
  __shared__ float ss[256], ss2[256];
  const int t = threadIdx.x, g = blockIdx.x;
  const float* p = y + (size_t)g * 32768;
  float s = 0.0f, s2 = 0.0f;
  for (int i = t; i < 32768; i += 256){ float v = p[i]; s += v; s2 += v * v; }
  ss[t] = s; ss2[t] = s2;
  __syncthreads();
  for (int off = 128; off > 0; off >>= 1){
    if (t < off){ ss[t] += ss[t + off]; ss2[t] += ss2[t + off]; }
    __syncthreads();
  }
  if (t == 0){
    float mu = ss[0] * (1.0f / 32768.0f);
    float var = ss2[0] * (1.0f / 32768.0f) - mu * mu;
    stats[g] = mu;
    stats[128 + g] = rsqrtf(var + 1e-5f);
  }
}

// ---------------------------------------------------------------------------
// Fused: InstanceNorm-apply + LeakyReLU + residual -> x1 (fp32 NCDHW)
// AND bf16 channels-last re-pack into xpad (input of conv2).
// ---------------------------------------------------------------------------
__global__ __launch_bounds__(256) void apply_pack_k(const float* __restrict__ xin,
    const float* __restrict__ y, const float* __restrict__ stats,
    float* __restrict__ x1, __hip_bfloat16* __restrict__ xpad)
{
  __shared__ float lds[64 * 33];
  const int t = threadIdx.x, blk = blockIdx.x;
  const int b = blk >> 10, h = (blk >> 5) & 31, w = blk & 31;
  const size_t rbase = ((size_t)(b * 64) << 15) + h * 1024 + w * 32;
  #pragma unroll
  for (int r = 0; r < 8; r++){
    int c = r * 8 + (t >> 5), d = t & 31;
    float mu = stats[b * 64 + c], rs = stats[128 + b * 64 + c];
    float v = (y[rbase + (size_t)c * 32768 + d] - mu) * rs;
    v = (v >= 0.0f) ? v : 0.01f * v;
    v += xin[rbase + (size_t)c * 32768 + d];
    x1[rbase + (size_t)c * 32768 + d] = v;
    lds[c * 33 + d] = v;
  }
  __syncthreads();
  const size_t wbase = (size_t)b * 2515456 + (size_t)(h + 1) * 73984 + (w + 1) * 2176 + 64;
  #pragma unroll
  for (int r = 0; r < 8; r++){
    int d = r * 4 + (t >> 6), c = t & 63;
    xpad[wbase + d * 64 + c] = __float2bfloat16(lds[c * 33 + d]);
  }
}

// ---------------------------------------------------------------------------
// Fused: InstanceNorm-apply + LeakyReLU + residual + LayerNorm over C
// -> bf16 channels-last lnx [pos][64]. x2 never materialized.
// ---------------------------------------------------------------------------
__global__ __launch_bounds__(256) void apply_ln_k(const float* __restrict__ x1,
    const float* __restrict__ y, const float* __restrict__ stats,
    const float* __restrict__ lnw, const float* __restrict__ lnb,
    __hip_bfloat16* __restrict__ lnx)
{
  __shared__ float lds[64 * 33];
  __shared__ float s_mu[32], s_rs[32];
  const int t = threadIdx.x, blk = blockIdx.x;
  const int b = blk >> 10, h = (blk >> 5) & 31, w = blk & 31;
  const size_t rbase = ((size_t)(b * 64) << 15) + h * 1024 + w * 32;
  #pragma unroll
  for (int r = 0; r < 8; r++){
    int c = r * 8 + (t >> 5), d = t & 31;
    float mu = stats[b * 64 + c], rs = stats[128 + b * 64 + c];
    float v = (y[rbase + (size_t)c * 32768 + d] - mu) * rs;
    v = (v >= 0.0f) ? v : 0.01f * v;
    lds[c * 33 + d] = v + x1[rbase + (size_t)c * 32768 + d];
  }
  __syncthreads();
  if (t < 32){
    float s = 0.f, s2 = 0.f;
    for (int c = 0; c < 64; c++){ float v = lds[c * 33 + t]; s += v; s2 += v * v; }
    float mu = s * (1.f / 64.f);
    float var = s2 * (1.f / 64.f) - mu * mu;
    s_mu[t] = mu; s_rs[t] = rsqrtf(var + 1e-5f);
  }
  __syncthreads();
  const int d = t >> 3, c0 = (t & 7) * 8;
  const int pos = b * 32768 + h * 1024 + w * 32 + d;
  const float mu = s_mu[d], rs = s_rs[d];
  short8 o;
  #pragma unroll
  for (int j = 0; j < 8; j++){
    int c = c0 + j;
    o[j] = f2b((lds[c * 33 + d] - mu) * rs * lnw[c] + lnb[c]);
  }
  *(short8*)&lnx[(size_t)pos * 64 + c0] = o;
}

// ---------------------------------------------------------------------------
// GEMM [65536,64] x [64,256] -> Lbuf (cols 0-127 raw) + Gbuf (silu, 128-255).
// ---------------------------------------------------------------------------
__global__ __launch_bounds__(256) void gemm_lr_k(const __hip_bfloat16* __restrict__ lnx,
    const __hip_bfloat16* __restrict__ Wlr, __hip_bfloat16* __restrict__ Lb,
    __hip_bfloat16* __restrict__ Gb)
{
  const int t = threadIdx.x, wave = t >> 6, lane = t & 63, quad = lane >> 4, ln = lane & 15;
  const int pos0 = blockIdx.x * 64 + wave * 16;
  f32x4 acc[16];
  #pragma unroll
  for (int nt = 0; nt < 16; nt++) acc[nt] = (f32x4){0.f, 0.f, 0.f, 0.f};
  #pragma unroll
  for (int ks = 0; ks < 2; ks++){
    short8 a = *(const short8*)&lnx[(size_t)(pos0 + ln) * 64 + ks * 32 + quad * 8];
    #pragma unroll
    for (int nt = 0; nt < 16; nt++){
      short8 bv = *(const short8*)&Wlr[(nt * 16 + ln) * 64 + ks * 32 + quad * 8];
      acc[nt] = __builtin_amdgcn_mfma_f32_16x16x32_bf16(a, bv, acc[nt], 0, 0, 0);
    }
  }
  #pragma unroll
  for (int nt = 0; nt < 16; nt++){
    int col = nt * 16 + ln;
    #pragma unroll
    for (int reg = 0; reg < 4; reg++){
      int pos = pos0 + quad * 4 + reg;
      float v = acc[nt][reg];
      if (col < 128) Lb[(size_t)pos * 128 + col] = __float2bfloat16(v);
      else           Gb[(size_t)pos * 128 + col - 128] = __float2bfloat16(siluf(v));
    }
  }
}

// ---------------------------------------------------------------------------
// FUSED per-axis: conv1d(k=4)+silu -> LDS tile -> GEMM [64,128]x[128,160].
// ---------------------------------------------------------------------------
__global__ __launch_bounds__(256) void dbc_k(const __hip_bfloat16* __restrict__ Lb,
    const float* __restrict__ cw, const float* __restrict__ cb,
    const __hip_bfloat16* __restrict__ Wd, const float* __restrict__ db,
    __hip_bfloat16* __restrict__ xl, __hip_bfloat16* __restrict__ dbc, int sh)
{
  __shared__ short s_xl[64 * 136];
  const int t = threadIdx.x;
  const int pos0 = blockIdx.x * 64;
  const int sigma = 1 << sh;

  #pragma unroll
  for (int r = 0; r < 4; r++){
    int i = t + r * 256;
    int pi = i >> 4, c0 = (i & 15) * 8;
    int pos = pos0 + pi;
    int l = (pos >> sh) & 31;
    float acc[8]; float4 w4[8];
    #pragma unroll
    for (int c = 0; c < 8; c++){ w4[c] = *(const float4*)&cw[(c0 + c) * 4]; acc[c] = cb[c0 + c]; }
    #pragma unroll
    for (int j = 0; j < 4; j++){
      int off = 3 - j;
      if (l >= off){
        short8 lv = *(const short8*)&Lb[(size_t)(pos - off * sigma) * 128 + c0];
        #pragma unroll
        for (int c = 0; c < 8; c++){
          float wv = (j == 0) ? w4[c].x : (j == 1) ? w4[c].y : (j == 2) ? w4[c].z : w4[c].w;
          acc[c] += wv * b2f(lv[c]);
        }
      }
    }
    short8 o;
    #pragma unroll
    for (int c = 0; c < 8; c++) o[c] = f2b(siluf(acc[c]));
    *(short8*)&s_xl[pi * 136 + c0] = o;
    *(short8*)&xl[(size_t)pos * 128 + c0] = o;
  }
  __syncthreads();

  const int wave = t >> 6, lane = t & 63, quad = lane >> 4, ln = lane & 15;
  const int rowb = (wave * 16 + ln) * 136;
  f32x4 acc2[10];
  #pragma unroll
  for (int nt = 0; nt < 10; nt++) acc2[nt] = (f32x4){0.f, 0.f, 0.f, 0.f};
  #pragma unroll
  for (int ks = 0; ks < 4; ks++){
    short8 a = *(const short8*)&s_xl[rowb + ks * 32 + quad * 8];
    #pragma unroll
    for (int nt = 0; nt < 10; nt++){
      short8 bv = *(const short8*)&Wd[(nt * 16 + ln) * 128 + ks * 32 + quad * 8];
      acc2[nt] = __builtin_amdgcn_mfma_f32_16x16x32_bf16(a, bv, acc2[nt], 0, 0, 0);
    }
  }
  const int posw = pos0 + wave * 16 + quad * 4;
  #pragma unroll
  for (int nt = 0; nt < 10; nt++){
    int col = nt * 16 + ln;
    bool isd = col < 128;
    float dbv = isd ? db[col] : 0.f;
    #pragma unroll
    for (int reg = 0; reg < 4; reg++){
      float v = acc2[nt][reg];
      if (isd) v = fminf(fmaxf(softplusf(v + dbv), 1e-4f), 10.f);
      dbc[(size_t)(posw + reg) * 160 + col] = __float2bfloat16(v);
    }
  }
}

// ---------------------------------------------------------------------------
// Per-axis selective scan + gate + post-LN -> Ybuf (pos-major, coalesced).
// 1 block (128 thr) per sequence.
// ---------------------------------------------------------------------------
__global__ __launch_bounds__(128) void scan_k(const __hip_bfloat16* __restrict__ dbc,
    const __hip_bfloat16* __restrict__ xl, const __hip_bfloat16* __restrict__ Gb,
    const float* __restrict__ alog, const float* __restrict__ pnw, const float* __restrict__ pnb,
    __hip_bfloat16* __restrict__ Yb, int axis)
{
  __shared__ float s_B[512], s_C[512], s_y[4128], s_mu[32], s_rs[32];
  const int t = threadIdx.x, seq = blockIdx.x;
  const int b = seq >> 10, r1 = (seq >> 5) & 31, r0 = seq & 31;
  int base, sigma;
  if (axis == 0){      base = b * 32768 + r1 * 32 + r0;        sigma = 1024; }
  else if (axis == 1){ base = b * 32768 + r1 * 1024 + r0;      sigma = 32; }
  else {               base = b * 32768 + r1 * 1024 + r0 * 32; sigma = 1; }

  for (int i = t; i < 1024; i += 128){
    int l = i >> 5, j = i & 31;
    float v = __bfloat162float(dbc[(size_t)(base + l * sigma) * 160 + 128 + j]);
    if (j < 16) s_B[l * 16 + j] = v; else s_C[l * 16 + (j - 16)] = v;
  }
  float A[16], h[16];
  #pragma unroll
  for (int s = 0; s < 16; s++){ A[s] = -softplusf(alog[s]); h[s] = 0.f; }
  __syncthreads();

  const int d = t;
  for (int l = 0; l < 32; l++){
    size_t row = (size_t)(base + l * sigma);
    float dt = __bfloat162float(dbc[row * 160 + d]);
    float xt = __bfloat162float(xl[row * 128 + d]);
    float g  = __bfloat162float(Gb[row * 128 + d]);
    float dx = dt * xt, yv = 0.f;
    #pragma unroll
    for (int s = 0; s < 16; s++){
      h[s] = __expf(dt * A[s]) * h[s] + dx * s_B[l * 16 + s];
      yv += h[s] * s_C[l * 16 + s];
    }
    s_y[l * 129 + d] = yv * g;
  }
  __syncthreads();
  if (t < 32){
    float s = 0.f, s2 = 0.f;
    for (int k = 0; k < 128; k++){ float v = s_y[t * 129 + k]; s += v; s2 += v * v; }
    float mu = s * (1.f / 128.f), var = s2 * (1.f / 128.f) - mu * mu;
    s_mu[t] = mu; s_rs[t] = rsqrtf(var + 1e-5f);
  }
  __syncthreads();
  const float pw = pnw[d], pb = pnb[d];
  for (int l = 0; l < 32; l++){
    float v = (s_y[l * 129 + d] - s_mu[l]) * s_rs[l] * pw + pb;
    Yb[(size_t)(base + l * sigma) * 128 + d] = __float2bfloat16(v);
  }
}

// ---------------------------------------------------------------------------
// GEMM out + weighted accumulate into d_out (pos-ordered -> coalesced).
// mode: 0=first (store), 1=middle (add), 2=last (add + residual finalize).
// ---------------------------------------------------------------------------
__global__ __launch_bounds__(256) void gemm_out_k(const __hip_bfloat16* __restrict__ Yb,
    const __hip_bfloat16* __restrict__ oW, const float* __restrict__ axw,
    const float* __restrict__ xres, const float* __restrict__ rsc,
    float* __restrict__ outp, int axis, int mode)
{
  const int t = threadIdx.x, wave = t >> 6, lane = t & 63, quad = lane >> 4, ln = lane & 15;
  const int pos0 = blockIdx.x * 64 + wave * 16;
  f32x4 acc[4];
  #pragma unroll
  for (int mt = 0; mt < 4; mt++) acc[mt] = (f32x4){0.f, 0.f, 0.f, 0.f};
  #pragma unroll
  for (int ks = 0; ks < 4; ks++){
    short8 bv = *(const short8*)&Yb[(size_t)(pos0 + ln) * 128 + ks * 32 + quad * 8];
    #pragma unroll
    for (int mt = 0; mt < 4; mt++){
      short8 a = *(const short8*)&oW[(mt * 16 + ln) * 128 + ks * 32 + quad * 8];
      acc[mt] = __builtin_amdgcn_mfma_f32_16x16x32_bf16(a, bv, acc[mt], 0, 0, 0);
    }
  }
  float a0 = axw[0], a1 = axw[1], a2 = axw[2];
  float mx = fmaxf(a0, fmaxf(a1, a2));
  float e0 = __expf(a0 - mx), e1 = __expf(a1 - mx), e2 = __expf(a2 - mx);
  float wax = ((axis == 0) ? e0 : (axis == 1) ? e1 : e2) / (e0 + e1 + e2);
  float rs = rsc[0];
  const int pos = pos0 + ln;
  const int bb = pos >> 15, hwd = pos & 32767;
  #pragma unroll
  for (int mt = 0; mt < 4; mt++){
    #pragma unroll
    for (int reg = 0; reg < 4; reg++){
      int co = mt * 16 + quad * 4 + reg;
      size_t idx = (((size_t)(bb * 64 + co)) << 15) + hwd;
      float v = acc[mt][reg] * wax;
      if (mode == 0)      outp[idx] = v;
      else if (mode == 1) outp[idx] += v;
      else                outp[idx] = xres[idx] + rs * (outp[idx] + v);
    }
  }
}

// ---------------------------------------------------------------------------
extern "C" void kernel_launch(void* const* d_in, const int* in_sizes, int n_in,
                              void* d_out, int out_size, void* d_ws, size_t ws_size,
                              hipStream_t stream)
{
  const float* x      = (const float*)d_in[0];
  const float* cr1w   = (const float*)d_in[1];
  const float* cr2w   = (const float*)d_in[3];
  const float* ln_w   = (const float*)d_in[5];
  const float* ln_b   = (const float*)d_in[6];
  const float* left_w = (const float*)d_in[7];
  const float* c1dw   = (const float*)d_in[8];
  const float* c1db   = (const float*)d_in[9];
  const float* dw     = (const float*)d_in[10];
  const float* db     = (const float*)d_in[11];
  const float* bpw    = (const float*)d_in[12];
  const float* cpw    = (const float*)d_in[13];
  const float* alog   = (const float*)d_in[14];
  const float* rw     = (const float*)d_in[15];
  const float* pnw    = (const float*)d_in[16];
  const float* pnb    = (const float*)d_in[17];
  const float* ow     = (const float*)d_in[18];
  const float* rsc    = (const float*)d_in[19];
  const float* axw    = (const float*)d_in[20];
  float* out = (float*)d_out;                       // conv raw out, then mamba accum
  float* wsf = (float*)d_ws;

  float* buf1   = wsf;                                         // x1 fp32; later xl bf16 alias
  float* stats  = wsf + 4194304;                               // 256 f
  __hip_bfloat16* W4a  = (__hip_bfloat16*)(wsf + 4194816);     // 110,592 bf16
  __hip_bfloat16* W4b  = W4a + 110592;
  __hip_bfloat16* Wlr  = (__hip_bfloat16*)(wsf + 4305408);     // 16,384 bf16
  __hip_bfloat16* Wdbc = (__hip_bfloat16*)(wsf + 4313600);     // 20,480 bf16
  __hip_bfloat16* oWp  = (__hip_bfloat16*)(wsf + 4323840);     // 8,192 bf16
  __hip_bfloat16* xpad = (__hip_bfloat16*)(wsf + 4327936);     // 5,030,912 bf16
  __hip_bfloat16* lnx  = xpad;                                 // alias (post-conv)
  __hip_bfloat16* Lbuf = (__hip_bfloat16*)(wsf + 6843392);     // 8,388,608 bf16
  __hip_bfloat16* Gbuf = (__hip_bfloat16*)(wsf + 11037696);    // 8,388,608 bf16
  __hip_bfloat16* dbc  = (__hip_bfloat16*)(wsf + 15232000);    // 10,485,760 bf16
  __hip_bfloat16* Ybuf = (__hip_bfloat16*)(wsf + 20474880);    // 8,388,608 bf16
  __hip_bfloat16* xl   = (__hip_bfloat16*)buf1;                // alias (x1 dead after apply_ln)

  setup_k<<<3497, 256, 0, stream>>>((uint4*)xpad, cr1w, cr2w, left_w, rw, dw, bpw, cpw, ow,
                                    W4a, W4b, Wlr, Wdbc, oWp);

  dim3 cgrid(256, 2, 2);
  // conv-res block 1
  pack_k<<<2048, 256, 0, stream>>>(x, xpad);
  conv_mfma_k<<<cgrid, 256, 0, stream>>>(xpad, W4a, out);
  inorm_stats_k<<<128, 256, 0, stream>>>(out, stats);
  apply_pack_k<<<2048, 256, 0, stream>>>(x, out, stats, buf1, xpad);
  // conv-res block 2 (fused apply + LayerNorm; x2 never materialized)
  conv_mfma_k<<<cgrid, 256, 0, stream>>>(xpad, W4b, out);
  inorm_stats_k<<<128, 256, 0, stream>>>(out, stats);
  apply_ln_k<<<2048, 256, 0, stream>>>(buf1, out, stats, ln_w, ln_b, lnx);

  // mamba: axis-independent projection once
  gemm_lr_k<<<1024, 256, 0, stream>>>(lnx, Wlr, Lbuf, Gbuf);

  // per-axis: dbc_k (conv1d+gemm fused) -> scan_k -> gemm_out_k (coalesced)
  const int sh[3] = {10, 5, 0};
  for (int axis = 0; axis < 3; axis++){
    dbc_k<<<1024, 256, 0, stream>>>(Lbuf, c1dw, c1db, Wdbc, db, xl, dbc, sh[axis]);
    scan_k<<<2048, 128, 0, stream>>>(dbc, xl, Gbuf, alog, pnw, pnb, Ybuf, axis);
    gemm_out_k<<<1024, 256, 0, stream>>>(Ybuf, oWp, axw, x, rsc, out, axis,
                                         axis == 0 ? 0 : (axis == 2 ? 2 : 1));
  }
}

// Round 8
// 673.042 us; speedup vs baseline: 1.3399x; 1.2695x over previous
//
#include <hip/hip_runtime.h>
#include <hip/hip_bf16.h>
#include <math.h>
#include <stdint.h>

// ---------------------------------------------------------------------------
// Full U-Mamba block. R8: conv rebuilt as m97-pattern LDS-staged MFMA GEMM
// (global_load_lds width=16, 2-barrier K-step, XCD-swizzled h-slices for L2
// residency). R5/R7 proven conv tile shape (64co x 128pos, 512 blocks).
// Everything else = R7 (best-known mamba pipeline).
// ---------------------------------------------------------------------------

typedef __attribute__((ext_vector_type(8))) short short8;   // 8 bf16 = 4 VGPR
typedef __attribute__((ext_vector_type(4))) float f32x4;

__device__ __forceinline__ float siluf(float x){ return x * (1.0f / (1.0f + __expf(-x))); }
__device__ __forceinline__ float softplusf(float x){ return fmaxf(x, 0.0f) + log1pf(__expf(-fabsf(x))); }
__device__ __forceinline__ float b2f(short s){
  unsigned int u = ((unsigned int)(unsigned short)s) << 16;
  float f; __builtin_memcpy(&f, &u, 4); return f;
}
__device__ __forceinline__ short f2b(float v){
  __hip_bfloat16 h = __float2bfloat16(v);
  unsigned short u; __builtin_memcpy(&u, &h, 2); return (short)u;
}

// async global->LDS, 16B per lane; LDS dest is wave-uniform base + lane*16
// (CK-style addrspace casts: generic->AS(1) via uintptr, generic LDS ->
// AS(3) via low-32-bit truncation).
__device__ __forceinline__ void gld_lds16(const void* g, void* l){
  __builtin_amdgcn_global_load_lds(
      (__attribute__((address_space(1))) void*)(uintptr_t)g,
      (__attribute__((address_space(3))) void*)(uint32_t)(uintptr_t)l,
      16, 0, 0);
}

// ---------------------------------------------------------------------------
// One-shot setup: zero xpad | pack conv weights a/b -> bf16 [tap][co][ci] |
// mamba weight bf16 tables.
// ---------------------------------------------------------------------------
__global__ __launch_bounds__(256) void setup_k(uint4* __restrict__ xz,
    const float* __restrict__ cr1w, const float* __restrict__ cr2w,
    const float* __restrict__ lw, const float* __restrict__ rwt,
    const float* __restrict__ dwt, const float* __restrict__ bw,
    const float* __restrict__ cwp, const float* __restrict__ owt,
    __hip_bfloat16* __restrict__ W4a, __hip_bfloat16* __restrict__ W4b,
    __hip_bfloat16* __restrict__ Wlr, __hip_bfloat16* __restrict__ Wd,
    __hip_bfloat16* __restrict__ oWp)
{
  int i = blockIdx.x * 256 + threadIdx.x;
  if (i < 628864){ uint4 z; z.x = z.y = z.z = z.w = 0u; xz[i] = z; return; }
  i -= 628864;
  if (i < 110592){
    int tap = i >> 12, co = (i >> 6) & 63, ci = i & 63;
    W4a[i] = __float2bfloat16(cr1w[(co * 64 + ci) * 27 + tap]); return;
  }
  i -= 110592;
  if (i < 110592){
    int tap = i >> 12, co = (i >> 6) & 63, ci = i & 63;
    W4b[i] = __float2bfloat16(cr2w[(co * 64 + ci) * 27 + tap]); return;
  }
  i -= 110592;
  if (i < 16384){
    int row = i >> 6, c = i & 63;
    float v = (row < 128) ? lw[row * 64 + c] : rwt[(row - 128) * 64 + c];
    Wlr[i] = __float2bfloat16(v); return;
  }
  i -= 16384;
  if (i < 20480){
    int row = i >> 7, k = i & 127;
    float v = (row < 128) ? dwt[row * 128 + k]
            : (row < 144 ? bw[(row - 128) * 128 + k] : cwp[(row - 144) * 128 + k]);
    Wd[i] = __float2bfloat16(v); return;
  }
  i -= 20480;
  if (i < 8192){ oWp[i] = __float2bfloat16(owt[i]); return; }
}

// ---------------------------------------------------------------------------
// Pack fp32 NCDHW -> padded channels-last bf16 [b][h+1][w+1][d+1][c] (conv1).
// ---------------------------------------------------------------------------
__global__ __launch_bounds__(256) void pack_k(const float* __restrict__ xin,
                                              __hip_bfloat16* __restrict__ xpad)
{
  __shared__ float lds[64 * 33];
  const int t = threadIdx.x, blk = blockIdx.x;
  const int b = blk >> 10, h = (blk >> 5) & 31, w = blk & 31;
  const size_t rbase = ((size_t)(b * 64) << 15) + h * 1024 + w * 32;
  #pragma unroll
  for (int r = 0; r < 8; r++){
    int c = r * 8 + (t >> 5), d = t & 31;
    lds[c * 33 + d] = xin[rbase + (size_t)c * 32768 + d];
  }
  __syncthreads();
  const size_t wbase = (size_t)b * 2515456 + (size_t)(h + 1) * 73984 + (w + 1) * 2176 + 64;
  #pragma unroll
  for (int r = 0; r < 8; r++){
    int d = r * 4 + (t >> 6), c = t & 63;
    xpad[wbase + d * 64 + c] = __float2bfloat16(lds[c * 33 + d]);
  }
}

// ---------------------------------------------------------------------------
// Conv3d implicit GEMM, bf16 MFMA 16x16x32, LDS-staged (m97 pattern).
// Grid 512 linear; XCD swizzle: xcd=blk&7 -> h in [xcd*4, xcd*4+4) so each
// XCD's B working set (~1.8MB) stays L2-resident. Block tile: 64co x 128pos
// (4 w-cols x 32 d). Per K-step (54 = 27 taps x 2 ci-halves):
//   stage B[128pos][32ci] (8KB, 2 instr/wave) + A[64co][32ci] (4KB, 1/wave)
//   via global_load_lds; sync; 6x ds_read_b128 + 8 MFMA per wave; sync.
// Bias canceled by InstanceNorm and dropped.
// ---------------------------------------------------------------------------
__global__ __launch_bounds__(256) void conv_mfma_k(const __hip_bfloat16* __restrict__ xpad,
    const __hip_bfloat16* __restrict__ W4, float* __restrict__ y)
{
  __shared__ short smem[6144];   // [0,4096): B tile; [4096,6144): A tile

  const int t = threadIdx.x;
  const int wave = t >> 6, lane = t & 63;
  const int quad = lane >> 4, ln = lane & 15;

  const int blk = blockIdx.x;          // 512 blocks
  const int xcd = blk & 7, j = blk >> 3;
  const int b = j >> 5, jj = j & 31;
  const int h = xcd * 4 + (jj >> 3);
  const int w0 = (jj & 7) * 4;

  // per-lane staging column offset: (lane>>2)*64 + (lane&3)*8 elements
  const int bcol = (lane >> 2) * 64 + (lane & 3) * 8;
  const __hip_bfloat16* Bg = xpad + (size_t)b * 2515456 + (size_t)h * 73984
                                  + (size_t)(w0 + wave) * 2176 + bcol;
  const __hip_bfloat16* Ag = W4 + wave * 1024 + bcol;
  short* Bl0 = &smem[wave * 1024];          // pos chunk 2*wave   (16 pos)
  short* Bl1 = &smem[wave * 1024 + 512];    // pos chunk 2*wave+1
  short* Al  = &smem[4096 + wave * 512];    // co  chunk wave

  f32x4 acc[2][4];
  #pragma unroll
  for (int jn = 0; jn < 2; jn++)
    #pragma unroll
    for (int m = 0; m < 4; m++) acc[jn][m] = (f32x4){0.f, 0.f, 0.f, 0.f};

  // consume offsets (shorts)
  const int aoff = ln * 32 + quad * 8;            // + mt*512 within A region
  const int boff = (wave * 32 + ln) * 32 + quad * 8;  // + jn*512

  for (int s = 0; s < 54; s++){
    const int t1 = s >> 1, ch = s & 1;
    const int ki = t1 / 9, kj = (t1 / 3) % 3, kk = t1 % 3;
    const int tapoff = ki * 73984 + kj * 2176 + kk * 64 + ch * 32;

    __syncthreads();                              // LDS free (prev consume done)
    gld_lds16(Bg + tapoff,        Bl0);
    gld_lds16(Bg + tapoff + 1024, Bl1);           // pos +16 rows (16*64 elems)
    gld_lds16(Ag + t1 * 4096 + ch * 32, Al);
    __syncthreads();                              // vmcnt(0) drained -> data visible

    short8 a0 = *(const short8*)&smem[4096 + aoff];
    short8 a1 = *(const short8*)&smem[4096 + 512 + aoff];
    short8 a2 = *(const short8*)&smem[4096 + 1024 + aoff];
    short8 a3 = *(const short8*)&smem[4096 + 1536 + aoff];
    short8 b0 = *(const short8*)&smem[boff];
    short8 b1 = *(const short8*)&smem[boff + 512];

    acc[0][0] = __builtin_amdgcn_mfma_f32_16x16x32_bf16(a0, b0, acc[0][0], 0, 0, 0);
    acc[0][1] = __builtin_amdgcn_mfma_f32_16x16x32_bf16(a1, b0, acc[0][1], 0, 0, 0);
    acc[0][2] = __builtin_amdgcn_mfma_f32_16x16x32_bf16(a2, b0, acc[0][2], 0, 0, 0);
    acc[0][3] = __builtin_amdgcn_mfma_f32_16x16x32_bf16(a3, b0, acc[0][3], 0, 0, 0);
    acc[1][0] = __builtin_amdgcn_mfma_f32_16x16x32_bf16(a0, b1, acc[1][0], 0, 0, 0);
    acc[1][1] = __builtin_amdgcn_mfma_f32_16x16x32_bf16(a1, b1, acc[1][1], 0, 0, 0);
    acc[1][2] = __builtin_amdgcn_mfma_f32_16x16x32_bf16(a2, b1, acc[1][2], 0, 0, 0);
    acc[1][3] = __builtin_amdgcn_mfma_f32_16x16x32_bf16(a3, b1, acc[1][3], 0, 0, 0);
  }

  // C/D: col = d (= jn*16+ln), row = co (quad*4+reg within 16-tile)
  const size_t sbase = (size_t)h * 1024 + (w0 + wave) * 32 + ln;
  #pragma unroll
  for (int jn = 0; jn < 2; jn++){
    #pragma unroll
    for (int mt = 0; mt < 4; mt++){
      #pragma unroll
      for (int reg = 0; reg < 4; reg++){
        int co = mt * 16 + quad * 4 + reg;
        y[(((size_t)(b * 64 + co)) << 15) + sbase + jn * 16] = acc[jn][mt][reg];
      }
    }
  }
}

// ---------------------------------------------------------------------------
// InstanceNorm3d stats: one block per (b,c); stats[g]=mu, stats[128+g]=rsigma.
// ---------------------------------------------------------------------------
__global__ __launch_bounds__(256) void inorm_stats_k(const float* __restrict__ y,
                                                     float* __restrict__ stats)
{
  __shared__ float ss[256], ss2[256];
  const int t = threadIdx.x, g = blockIdx.x;
  const float* p = y + (size_t)g * 32768;
  float s = 0.0f, s2 = 0.0f;
  for (int i = t; i < 32768; i += 256){ float v = p[i]; s += v; s2 += v * v; }
  ss[t] = s; ss2[t] = s2;
  __syncthreads();
  for (int off = 128; off > 0; off >>= 1){
    if (t < off){ ss[t] += ss[t + off]; ss2[t] += ss2[t + off]; }
    __syncthreads();
  }
  if (t == 0){
    float mu = ss[0] * (1.0f / 32768.0f);
    float var = ss2[0] * (1.0f / 32768.0f) - mu * mu;
    stats[g] = mu;
    stats[128 + g] = rsqrtf(var + 1e-5f);
  }
}

// ---------------------------------------------------------------------------
// Fused: InstanceNorm-apply + LeakyReLU + residual -> x1 (fp32 NCDHW)
// AND bf16 channels-last re-pack into xpad (input of conv2).
// ---------------------------------------------------------------------------
__global__ __launch_bounds__(256) void apply_pack_k(const float* __restrict__ xin,
    const float* __restrict__ y, const float* __restrict__ stats,
    float* __restrict__ x1, __hip_bfloat16* __restrict__ xpad)
{
  __shared__ float lds[64 * 33];
  const int t = threadIdx.x, blk = blockIdx.x;
  const int b = blk >> 10, h = (blk >> 5) & 31, w = blk & 31;
  const size_t rbase = ((size_t)(b * 64) << 15) + h * 1024 + w * 32;
  #pragma unroll
  for (int r = 0; r < 8; r++){
    int c = r * 8 + (t >> 5), d = t & 31;
    float mu = stats[b * 64 + c], rs = stats[128 + b * 64 + c];
    float v = (y[rbase + (size_t)c * 32768 + d] - mu) * rs;
    v = (v >= 0.0f) ? v : 0.01f * v;
    v += xin[rbase + (size_t)c * 32768 + d];
    x1[rbase + (size_t)c * 32768 + d] = v;
    lds[c * 33 + d] = v;
  }
  __syncthreads();
  const size_t wbase = (size_t)b * 2515456 + (size_t)(h + 1) * 73984 + (w + 1) * 2176 + 64;
  #pragma unroll
  for (int r = 0; r < 8; r++){
    int d = r * 4 + (t >> 6), c = t & 63;
    xpad[wbase + d * 64 + c] = __float2bfloat16(lds[c * 33 + d]);
  }
}

// ---------------------------------------------------------------------------
// Fused: InstanceNorm-apply + LeakyReLU + residual + LayerNorm over C
// -> bf16 channels-last lnx [pos][64]. x2 never materialized.
// ---------------------------------------------------------------------------
__global__ __launch_bounds__(256) void apply_ln_k(const float* __restrict__ x1,
    const float* __restrict__ y, const float* __restrict__ stats,
    const float* __restrict__ lnw, const float* __restrict__ lnb,
    __hip_bfloat16* __restrict__ lnx)
{
  __shared__ float lds[64 * 33];
  __shared__ float s_mu[32], s_rs[32];
  const int t = threadIdx.x, blk = blockIdx.x;
  const int b = blk >> 10, h = (blk >> 5) & 31, w = blk & 31;
  const size_t rbase = ((size_t)(b * 64) << 15) + h * 1024 + w * 32;
  #pragma unroll
  for (int r = 0; r < 8; r++){
    int c = r * 8 + (t >> 5), d = t & 31;
    float mu = stats[b * 64 + c], rs = stats[128 + b * 64 + c];
    float v = (y[rbase + (size_t)c * 32768 + d] - mu) * rs;
    v = (v >= 0.0f) ? v : 0.01f * v;
    lds[c * 33 + d] = v + x1[rbase + (size_t)c * 32768 + d];
  }
  __syncthreads();
  if (t < 32){
    float s = 0.f, s2 = 0.f;
    for (int c = 0; c < 64; c++){ float v = lds[c * 33 + t]; s += v; s2 += v * v; }
    float mu = s * (1.f / 64.f);
    float var = s2 * (1.f / 64.f) - mu * mu;
    s_mu[t] = mu; s_rs[t] = rsqrtf(var + 1e-5f);
  }
  __syncthreads();
  const int d = t >> 3, c0 = (t & 7) * 8;
  const int pos = b * 32768 + h * 1024 + w * 32 + d;
  const float mu = s_mu[d], rs = s_rs[d];
  short8 o;
  #pragma unroll
  for (int j = 0; j < 8; j++){
    int c = c0 + j;
    o[j] = f2b((lds[c * 33 + d] - mu) * rs * lnw[c] + lnb[c]);
  }
  *(short8*)&lnx[(size_t)pos * 64 + c0] = o;
}

// ---------------------------------------------------------------------------
// GEMM [65536,64] x [64,256] -> Lbuf (cols 0-127 raw) + Gbuf (silu, 128-255).
// ---------------------------------------------------------------------------
__global__ __launch_bounds__(256) void gemm_lr_k(const __hip_bfloat16* __restrict__ lnx,
    const __hip_bfloat16* __restrict__ Wlr, __hip_bfloat16* __restrict__ Lb,
    __hip_bfloat16* __restrict__ Gb)
{
  const int t = threadIdx.x, wave = t >> 6, lane = t & 63, quad = lane >> 4, ln = lane & 15;
  const int pos0 = blockIdx.x * 64 + wave * 16;
  f32x4 acc[16];
  #pragma unroll
  for (int nt = 0; nt < 16; nt++) acc[nt] = (f32x4){0.f, 0.f, 0.f, 0.f};
  #pragma unroll
  for (int ks = 0; ks < 2; ks++){
    short8 a = *(const short8*)&lnx[(size_t)(pos0 + ln) * 64 + ks * 32 + quad * 8];
    #pragma unroll
    for (int nt = 0; nt < 16; nt++){
      short8 bv = *(const short8*)&Wlr[(nt * 16 + ln) * 64 + ks * 32 + quad * 8];
      acc[nt] = __builtin_amdgcn_mfma_f32_16x16x32_bf16(a, bv, acc[nt], 0, 0, 0);
    }
  }
  #pragma unroll
  for (int nt = 0; nt < 16; nt++){
    int col = nt * 16 + ln;
    #pragma unroll
    for (int reg = 0; reg < 4; reg++){
      int pos = pos0 + quad * 4 + reg;
      float v = acc[nt][reg];
      if (col < 128) Lb[(size_t)pos * 128 + col] = __float2bfloat16(v);
      else           Gb[(size_t)pos * 128 + col - 128] = __float2bfloat16(siluf(v));
    }
  }
}

// ---------------------------------------------------------------------------
// FUSED per-axis: conv1d(k=4)+silu -> LDS tile -> GEMM [64,128]x[128,160].
// ---------------------------------------------------------------------------
__global__ __launch_bounds__(256) void dbc_k(const __hip_bfloat16* __restrict__ Lb,
    const float* __restrict__ cw, const float* __restrict__ cb,
    const __hip_bfloat16* __restrict__ Wd, const float* __restrict__ db,
    __hip_bfloat16* __restrict__ xl, __hip_bfloat16* __restrict__ dbc, int sh)
{
  __shared__ short s_xl[64 * 136];
  const int t = threadIdx.x;
  const int pos0 = blockIdx.x * 64;
  const int sigma = 1 << sh;

  #pragma unroll
  for (int r = 0; r < 4; r++){
    int i = t + r * 256;
    int pi = i >> 4, c0 = (i & 15) * 8;
    int pos = pos0 + pi;
    int l = (pos >> sh) & 31;
    float acc[8]; float4 w4[8];
    #pragma unroll
    for (int c = 0; c < 8; c++){ w4[c] = *(const float4*)&cw[(c0 + c) * 4]; acc[c] = cb[c0 + c]; }
    #pragma unroll
    for (int j = 0; j < 4; j++){
      int off = 3 - j;
      if (l >= off){
        short8 lv = *(const short8*)&Lb[(size_t)(pos - off * sigma) * 128 + c0];
        #pragma unroll
        for (int c = 0; c < 8; c++){
          float wv = (j == 0) ? w4[c].x : (j == 1) ? w4[c].y : (j == 2) ? w4[c].z : w4[c].w;
          acc[c] += wv * b2f(lv[c]);
        }
      }
    }
    short8 o;
    #pragma unroll
    for (int c = 0; c < 8; c++) o[c] = f2b(siluf(acc[c]));
    *(short8*)&s_xl[pi * 136 + c0] = o;
    *(short8*)&xl[(size_t)pos * 128 + c0] = o;
  }
  __syncthreads();

  const int wave = t >> 6, lane = t & 63, quad = lane >> 4, ln = lane & 15;
  const int rowb = (wave * 16 + ln) * 136;
  f32x4 acc2[10];
  #pragma unroll
  for (int nt = 0; nt < 10; nt++) acc2[nt] = (f32x4){0.f, 0.f, 0.f, 0.f};
  #pragma unroll
  for (int ks = 0; ks < 4; ks++){
    short8 a = *(const short8*)&s_xl[rowb + ks * 32 + quad * 8];
    #pragma unroll
    for (int nt = 0; nt < 10; nt++){
      short8 bv = *(const short8*)&Wd[(nt * 16 + ln) * 128 + ks * 32 + quad * 8];
      acc2[nt] = __builtin_amdgcn_mfma_f32_16x16x32_bf16(a, bv, acc2[nt], 0, 0, 0);
    }
  }
  const int posw = pos0 + wave * 16 + quad * 4;
  #pragma unroll
  for (int nt = 0; nt < 10; nt++){
    int col = nt * 16 + ln;
    bool isd = col < 128;
    float dbv = isd ? db[col] : 0.f;
    #pragma unroll
    for (int reg = 0; reg < 4; reg++){
      float v = acc2[nt][reg];
      if (isd) v = fminf(fmaxf(softplusf(v + dbv), 1e-4f), 10.f);
      dbc[(size_t)(posw + reg) * 160 + col] = __float2bfloat16(v);
    }
  }
}

// ---------------------------------------------------------------------------
// Per-axis selective scan + gate + post-LN -> Ybuf (pos-major, coalesced).
// 1 block (128 thr) per sequence.
// ---------------------------------------------------------------------------
__global__ __launch_bounds__(128) void scan_k(const __hip_bfloat16* __restrict__ dbc,
    const __hip_bfloat16* __restrict__ xl, const __hip_bfloat16* __restrict__ Gb,
    const float* __restrict__ alog, const float* __restrict__ pnw, const float* __restrict__ pnb,
    __hip_bfloat16* __restrict__ Yb, int axis)
{
  __shared__ float s_B[512], s_C[512], s_y[4128], s_mu[32], s_rs[32];
  const int t = threadIdx.x, seq = blockIdx.x;
  const int b = seq >> 10, r1 = (seq >> 5) & 31, r0 = seq & 31;
  int base, sigma;
  if (axis == 0){      base = b * 32768 + r1 * 32 + r0;        sigma = 1024; }
  else if (axis == 1){ base = b * 32768 + r1 * 1024 + r0;      sigma = 32; }
  else {               base = b * 32768 + r1 * 1024 + r0 * 32; sigma = 1; }

  for (int i = t; i < 1024; i += 128){
    int l = i >> 5, j = i & 31;
    float v = __bfloat162float(dbc[(size_t)(base + l * sigma) * 160 + 128 + j]);
    if (j < 16) s_B[l * 16 + j] = v; else s_C[l * 16 + (j - 16)] = v;
  }
  float A[16], h[16];
  #pragma unroll
  for (int s = 0; s < 16; s++){ A[s] = -softplusf(alog[s]); h[s] = 0.f; }
  __syncthreads();

  const int d = t;
  for (int l = 0; l < 32; l++){
    size_t row = (size_t)(base + l * sigma);
    float dt = __bfloat162float(dbc[row * 160 + d]);
    float xt = __bfloat162float(xl[row * 128 + d]);
    float g  = __bfloat162float(Gb[row * 128 + d]);
    float dx = dt * xt, yv = 0.f;
    #pragma unroll
    for (int s = 0; s < 16; s++){
      h[s] = __expf(dt * A[s]) * h[s] + dx * s_B[l * 16 + s];
      yv += h[s] * s_C[l * 16 + s];
    }
    s_y[l * 129 + d] = yv * g;
  }
  __syncthreads();
  if (t < 32){
    float s = 0.f, s2 = 0.f;
    for (int k = 0; k < 128; k++){ float v = s_y[t * 129 + k]; s += v; s2 += v * v; }
    float mu = s * (1.f / 128.f), var = s2 * (1.f / 128.f) - mu * mu;
    s_mu[t] = mu; s_rs[t] = rsqrtf(var + 1e-5f);
  }
  __syncthreads();
  const float pw = pnw[d], pb = pnb[d];
  for (int l = 0; l < 32; l++){
    float v = (s_y[l * 129 + d] - s_mu[l]) * s_rs[l] * pw + pb;
    Yb[(size_t)(base + l * sigma) * 128 + d] = __float2bfloat16(v);
  }
}

// ---------------------------------------------------------------------------
// GEMM out + weighted accumulate into d_out (pos-ordered -> coalesced).
// mode: 0=first (store), 1=middle (add), 2=last (add + residual finalize).
// ---------------------------------------------------------------------------
__global__ __launch_bounds__(256) void gemm_out_k(const __hip_bfloat16* __restrict__ Yb,
    const __hip_bfloat16* __restrict__ oW, const float* __restrict__ axw,
    const float* __restrict__ xres, const float* __restrict__ rsc,
    float* __restrict__ outp, int axis, int mode)
{
  const int t = threadIdx.x, wave = t >> 6, lane = t & 63, quad = lane >> 4, ln = lane & 15;
  const int pos0 = blockIdx.x * 64 + wave * 16;
  f32x4 acc[4];
  #pragma unroll
  for (int mt = 0; mt < 4; mt++) acc[mt] = (f32x4){0.f, 0.f, 0.f, 0.f};
  #pragma unroll
  for (int ks = 0; ks < 4; ks++){
    short8 bv = *(const short8*)&Yb[(size_t)(pos0 + ln) * 128 + ks * 32 + quad * 8];
    #pragma unroll
    for (int mt = 0; mt < 4; mt++){
      short8 a = *(const short8*)&oW[(mt * 16 + ln) * 128 + ks * 32 + quad * 8];
      acc[mt] = __builtin_amdgcn_mfma_f32_16x16x32_bf16(a, bv, acc[mt], 0, 0, 0);
    }
  }
  float a0 = axw[0], a1 = axw[1], a2 = axw[2];
  float mx = fmaxf(a0, fmaxf(a1, a2));
  float e0 = __expf(a0 - mx), e1 = __expf(a1 - mx), e2 = __expf(a2 - mx);
  float wax = ((axis == 0) ? e0 : (axis == 1) ? e1 : e2) / (e0 + e1 + e2);
  float rs = rsc[0];
  const int pos = pos0 + ln;
  const int bb = pos >> 15, hwd = pos & 32767;
  #pragma unroll
  for (int mt = 0; mt < 4; mt++){
    #pragma unroll
    for (int reg = 0; reg < 4; reg++){
      int co = mt * 16 + quad * 4 + reg;
      size_t idx = (((size_t)(bb * 64 + co)) << 15) + hwd;
      float v = acc[mt][reg] * wax;
      if (mode == 0)      outp[idx] = v;
      else if (mode == 1) outp[idx] += v;
      else                outp[idx] = xres[idx] + rs * (outp[idx] + v);
    }
  }
}

// ---------------------------------------------------------------------------
extern "C" void kernel_launch(void* const* d_in, const int* in_sizes, int n_in,
                              void* d_out, int out_size, void* d_ws, size_t ws_size,
                              hipStream_t stream)
{
  const float* x      = (const float*)d_in[0];
  const float* cr1w   = (const float*)d_in[1];
  const float* cr2w   = (const float*)d_in[3];
  const float* ln_w   = (const float*)d_in[5];
  const float* ln_b   = (const float*)d_in[6];
  const float* left_w = (const float*)d_in[7];
  const float* c1dw   = (const float*)d_in[8];
  const float* c1db   = (const float*)d_in[9];
  const float* dw     = (const float*)d_in[10];
  const float* db     = (const float*)d_in[11];
  const float* bpw    = (const float*)d_in[12];
  const float* cpw    = (const float*)d_in[13];
  const float* alog   = (const float*)d_in[14];
  const float* rw     = (const float*)d_in[15];
  const float* pnw    = (const float*)d_in[16];
  const float* pnb    = (const float*)d_in[17];
  const float* ow     = (const float*)d_in[18];
  const float* rsc    = (const float*)d_in[19];
  const float* axw    = (const float*)d_in[20];
  float* out = (float*)d_out;                       // conv raw out, then mamba accum
  float* wsf = (float*)d_ws;

  float* buf1   = wsf;                                         // x1 fp32; later xl bf16 alias
  float* stats  = wsf + 4194304;                               // 256 f
  __hip_bfloat16* W4a  = (__hip_bfloat16*)(wsf + 4194816);     // 110,592 bf16
  __hip_bfloat16* W4b  = W4a + 110592;
  __hip_bfloat16* Wlr  = (__hip_bfloat16*)(wsf + 4305408);     // 16,384 bf16
  __hip_bfloat16* Wdbc = (__hip_bfloat16*)(wsf + 4313600);     // 20,480 bf16
  __hip_bfloat16* oWp  = (__hip_bfloat16*)(wsf + 4323840);     // 8,192 bf16
  __hip_bfloat16* xpad = (__hip_bfloat16*)(wsf + 4327936);     // 5,030,912 bf16
  __hip_bfloat16* lnx  = xpad;                                 // alias (post-conv)
  __hip_bfloat16* Lbuf = (__hip_bfloat16*)(wsf + 6843392);     // 8,388,608 bf16
  __hip_bfloat16* Gbuf = (__hip_bfloat16*)(wsf + 11037696);    // 8,388,608 bf16
  __hip_bfloat16* dbc  = (__hip_bfloat16*)(wsf + 15232000);    // 10,485,760 bf16
  __hip_bfloat16* Ybuf = (__hip_bfloat16*)(wsf + 20474880);    // 8,388,608 bf16
  __hip_bfloat16* xl   = (__hip_bfloat16*)buf1;                // alias (x1 dead after apply_ln)

  setup_k<<<3497, 256, 0, stream>>>((uint4*)xpad, cr1w, cr2w, left_w, rw, dw, bpw, cpw, ow,
                                    W4a, W4b, Wlr, Wdbc, oWp);

  // conv-res block 1
  pack_k<<<2048, 256, 0, stream>>>(x, xpad);
  conv_mfma_k<<<512, 256, 0, stream>>>(xpad, W4a, out);
  inorm_stats_k<<<128, 256, 0, stream>>>(out, stats);
  apply_pack_k<<<2048, 256, 0, stream>>>(x, out, stats, buf1, xpad);
  // conv-res block 2 (fused apply + LayerNorm; x2 never materialized)
  conv_mfma_k<<<512, 256, 0, stream>>>(xpad, W4b, out);
  inorm_stats_k<<<128, 256, 0, stream>>>(out, stats);
  apply_ln_k<<<2048, 256, 0, stream>>>(buf1, out, stats, ln_w, ln_b, lnx);

  // mamba: axis-independent projection once
  gemm_lr_k<<<1024, 256, 0, stream>>>(lnx, Wlr, Lbuf, Gbuf);

  // per-axis: dbc_k (conv1d+gemm fused) -> scan_k -> gemm_out_k (coalesced)
  const int sh[3] = {10, 5, 0};
  for (int axis = 0; axis < 3; axis++){
    dbc_k<<<1024, 256, 0, stream>>>(Lbuf, c1dw, c1db, Wdbc, db, xl, dbc, sh[axis]);
    scan_k<<<2048, 128, 0, stream>>>(dbc, xl, Gbuf, alog, pnw, pnb, Ybuf, axis);
    gemm_out_k<<<1024, 256, 0, stream>>>(Ybuf, oWp, axw, x, rsc, out, axis,
                                         axis == 0 ? 0 : (axis == 2 ? 2 : 1));
  }
}

// Round 9
// 658.841 us; speedup vs baseline: 1.3688x; 1.0216x over previous
//
#include <hip/hip_runtime.h>
#include <hip/hip_bf16.h>
#include <math.h>
#include <stdint.h>

// ---------------------------------------------------------------------------
// Full U-Mamba block. R9: scan_k rebuilt (bf16 y-staging 21->14KB LDS,
// parallel post-LN stats, vectorized B/C staging, precomputed negA*log2e +
// exp2f); dbc_k weight loads hoisted out of r-loop. Conv = R8 m97-pattern
// LDS-staged MFMA (kept). Pipeline structure = R7/R8.
// ---------------------------------------------------------------------------

typedef __attribute__((ext_vector_type(8))) short short8;   // 8 bf16 = 4 VGPR
typedef __attribute__((ext_vector_type(4))) float f32x4;

__device__ __forceinline__ float siluf(float x){ return x * (1.0f / (1.0f + __expf(-x))); }
__device__ __forceinline__ float softplusf(float x){ return fmaxf(x, 0.0f) + log1pf(__expf(-fabsf(x))); }
__device__ __forceinline__ float b2f(short s){
  unsigned int u = ((unsigned int)(unsigned short)s) << 16;
  float f; __builtin_memcpy(&f, &u, 4); return f;
}
__device__ __forceinline__ short f2b(float v){
  __hip_bfloat16 h = __float2bfloat16(v);
  unsigned short u; __builtin_memcpy(&u, &h, 2); return (short)u;
}

// async global->LDS, 16B per lane; LDS dest is wave-uniform base + lane*16.
__device__ __forceinline__ void gld_lds16(const void* g, void* l){
  __builtin_amdgcn_global_load_lds(
      (__attribute__((address_space(1))) void*)(uintptr_t)g,
      (__attribute__((address_space(3))) void*)(uint32_t)(uintptr_t)l,
      16, 0, 0);
}

// ---------------------------------------------------------------------------
// One-shot setup: zero xpad | pack conv weights a/b -> bf16 [tap][co][ci] |
// mamba weight bf16 tables | negA2[s] = -softplus(A_log[s]) * log2(e).
// ---------------------------------------------------------------------------
__global__ __launch_bounds__(256) void setup_k(uint4* __restrict__ xz,
    const float* __restrict__ cr1w, const float* __restrict__ cr2w,
    const float* __restrict__ lw, const float* __restrict__ rwt,
    const float* __restrict__ dwt, const float* __restrict__ bw,
    const float* __restrict__ cwp, const float* __restrict__ owt,
    const float* __restrict__ alog,
    __hip_bfloat16* __restrict__ W4a, __hip_bfloat16* __restrict__ W4b,
    __hip_bfloat16* __restrict__ Wlr, __hip_bfloat16* __restrict__ Wd,
    __hip_bfloat16* __restrict__ oWp, float* __restrict__ negA2)
{
  int i = blockIdx.x * 256 + threadIdx.x;
  if (i < 628864){ uint4 z; z.x = z.y = z.z = z.w = 0u; xz[i] = z; return; }
  i -= 628864;
  if (i < 110592){
    int tap = i >> 12, co = (i >> 6) & 63, ci = i & 63;
    W4a[i] = __float2bfloat16(cr1w[(co * 64 + ci) * 27 + tap]); return;
  }
  i -= 110592;
  if (i < 110592){
    int tap = i >> 12, co = (i >> 6) & 63, ci = i & 63;
    W4b[i] = __float2bfloat16(cr2w[(co * 64 + ci) * 27 + tap]); return;
  }
  i -= 110592;
  if (i < 16384){
    int row = i >> 6, c = i & 63;
    float v = (row < 128) ? lw[row * 64 + c] : rwt[(row - 128) * 64 + c];
    Wlr[i] = __float2bfloat16(v); return;
  }
  i -= 16384;
  if (i < 20480){
    int row = i >> 7, k = i & 127;
    float v = (row < 128) ? dwt[row * 128 + k]
            : (row < 144 ? bw[(row - 128) * 128 + k] : cwp[(row - 144) * 128 + k]);
    Wd[i] = __float2bfloat16(v); return;
  }
  i -= 20480;
  if (i < 8192){ oWp[i] = __float2bfloat16(owt[i]); return; }
  i -= 8192;
  if (i < 16){ negA2[i] = -softplusf(alog[i]) * 1.44269504088896f; return; }
}

// ---------------------------------------------------------------------------
// Pack fp32 NCDHW -> padded channels-last bf16 [b][h+1][w+1][d+1][c] (conv1).
// ---------------------------------------------------------------------------
__global__ __launch_bounds__(256) void pack_k(const float* __restrict__ xin,
                                              __hip_bfloat16* __restrict__ xpad)
{
  __shared__ float lds[64 * 33];
  const int t = threadIdx.x, blk = blockIdx.x;
  const int b = blk >> 10, h = (blk >> 5) & 31, w = blk & 31;
  const size_t rbase = ((size_t)(b * 64) << 15) + h * 1024 + w * 32;
  #pragma unroll
  for (int r = 0; r < 8; r++){
    int c = r * 8 + (t >> 5), d = t & 31;
    lds[c * 33 + d] = xin[rbase + (size_t)c * 32768 + d];
  }
  __syncthreads();
  const size_t wbase = (size_t)b * 2515456 + (size_t)(h + 1) * 73984 + (w + 1) * 2176 + 64;
  #pragma unroll
  for (int r = 0; r < 8; r++){
    int d = r * 4 + (t >> 6), c = t & 63;
    xpad[wbase + d * 64 + c] = __float2bfloat16(lds[c * 33 + d]);
  }
}

// ---------------------------------------------------------------------------
// Conv3d implicit GEMM, bf16 MFMA 16x16x32, LDS-staged (m97 pattern, R8).
// ---------------------------------------------------------------------------
__global__ __launch_bounds__(256) void conv_mfma_k(const __hip_bfloat16* __restrict__ xpad,
    const __hip_bfloat16* __restrict__ W4, float* __restrict__ y)
{
  __shared__ short smem[6144];   // [0,4096): B tile; [4096,6144): A tile

  const int t = threadIdx.x;
  const int wave = t >> 6, lane = t & 63;
  const int quad = lane >> 4, ln = lane & 15;

  const int blk = blockIdx.x;          // 512 blocks
  const int xcd = blk & 7, j = blk >> 3;
  const int b = j >> 5, jj = j & 31;
  const int h = xcd * 4 + (jj >> 3);
  const int w0 = (jj & 7) * 4;

  const int bcol = (lane >> 2) * 64 + (lane & 3) * 8;
  const __hip_bfloat16* Bg = xpad + (size_t)b * 2515456 + (size_t)h * 73984
                                  + (size_t)(w0 + wave) * 2176 + bcol;
  const __hip_bfloat16* Ag = W4 + wave * 1024 + bcol;
  short* Bl0 = &smem[wave * 1024];
  short* Bl1 = &smem[wave * 1024 + 512];
  short* Al  = &smem[4096 + wave * 512];

  f32x4 acc[2][4];
  #pragma unroll
  for (int jn = 0; jn < 2; jn++)
    #pragma unroll
    for (int m = 0; m < 4; m++) acc[jn][m] = (f32x4){0.f, 0.f, 0.f, 0.f};

  const int aoff = ln * 32 + quad * 8;
  const int boff = (wave * 32 + ln) * 32 + quad * 8;

  for (int s = 0; s < 54; s++){
    const int t1 = s >> 1, ch = s & 1;
    const int ki = t1 / 9, kj = (t1 / 3) % 3, kk = t1 % 3;
    const int tapoff = ki * 73984 + kj * 2176 + kk * 64 + ch * 32;

    __syncthreads();
    gld_lds16(Bg + tapoff,        Bl0);
    gld_lds16(Bg + tapoff + 1024, Bl1);
    gld_lds16(Ag + t1 * 4096 + ch * 32, Al);
    __syncthreads();

    short8 a0 = *(const short8*)&smem[4096 + aoff];
    short8 a1 = *(const short8*)&smem[4096 + 512 + aoff];
    short8 a2 = *(const short8*)&smem[4096 + 1024 + aoff];
    short8 a3 = *(const short8*)&smem[4096 + 1536 + aoff];
    short8 b0 = *(const short8*)&smem[boff];
    short8 b1 = *(const short8*)&smem[boff + 512];

    acc[0][0] = __builtin_amdgcn_mfma_f32_16x16x32_bf16(a0, b0, acc[0][0], 0, 0, 0);
    acc[0][1] = __builtin_amdgcn_mfma_f32_16x16x32_bf16(a1, b0, acc[0][1], 0, 0, 0);
    acc[0][2] = __builtin_amdgcn_mfma_f32_16x16x32_bf16(a2, b0, acc[0][2], 0, 0, 0);
    acc[0][3] = __builtin_amdgcn_mfma_f32_16x16x32_bf16(a3, b0, acc[0][3], 0, 0, 0);
    acc[1][0] = __builtin_amdgcn_mfma_f32_16x16x32_bf16(a0, b1, acc[1][0], 0, 0, 0);
    acc[1][1] = __builtin_amdgcn_mfma_f32_16x16x32_bf16(a1, b1, acc[1][1], 0, 0, 0);
    acc[1][2] = __builtin_amdgcn_mfma_f32_16x16x32_bf16(a2, b1, acc[1][2], 0, 0, 0);
    acc[1][3] = __builtin_amdgcn_mfma_f32_16x16x32_bf16(a3, b1, acc[1][3], 0, 0, 0);
  }

  const size_t sbase = (size_t)h * 1024 + (w0 + wave) * 32 + ln;
  #pragma unroll
  for (int jn = 0; jn < 2; jn++){
    #pragma unroll
    for (int mt = 0; mt < 4; mt++){
      #pragma unroll
      for (int reg = 0; reg < 4; reg++){
        int co = mt * 16 + quad * 4 + reg;
        y[(((size_t)(b * 64 + co)) << 15) + sbase + jn * 16] = acc[jn][mt][reg];
      }
    }
  }
}

// ---------------------------------------------------------------------------
// InstanceNorm3d stats: one block per (b,c); stats[g]=mu, stats[128+g]=rsigma.
// ---------------------------------------------------------------------------
__global__ __launch_bounds__(256) void inorm_stats_k(const float* __restrict__ y,
                                                     float* __restrict__ stats)
{
  __shared__ float ss[256], ss2[256];
  const int t = threadIdx.x, g = blockIdx.x;
  const float* p = y + (size_t)g * 32768;
  float s = 0.0f, s2 = 0.0f;
  for (int i = t; i < 32768; i += 256){ float v = p[i]; s += v; s2 += v * v; }
  ss[t] = s; ss2[t] = s2;
  __syncthreads();
  for (int off = 128; off > 0; off >>= 1){
    if (t < off){ ss[t] += ss[t + off]; ss2[t] += ss2[t + off]; }
    __syncthreads();
  }
  if (t == 0){
    float mu = ss[0] * (1.0f / 32768.0f);
    float var = ss2[0] * (1.0f / 32768.0f) - mu * mu;
    stats[g] = mu;
    stats[128 + g] = rsqrtf(var + 1e-5f);
  }
}

// ---------------------------------------------------------------------------
// Fused: InstanceNorm-apply + LeakyReLU + residual -> x1 (fp32 NCDHW)
// AND bf16 channels-last re-pack into xpad (input of conv2).
// ---------------------------------------------------------------------------
__global__ __launch_bounds__(256) void apply_pack_k(const float* __restrict__ xin,
    const float* __restrict__ y, const float* __restrict__ stats,
    float* __restrict__ x1, __hip_bfloat16* __restrict__ xpad)
{
  __shared__ float lds[64 * 33];
  const int t = threadIdx.x, blk = blockIdx.x;
  const int b = blk >> 10, h = (blk >> 5) & 31, w = blk & 31;
  const size_t rbase = ((size_t)(b * 64) << 15) + h * 1024 + w * 32;
  #pragma unroll
  for (int r = 0; r < 8; r++){
    int c = r * 8 + (t >> 5), d = t & 31;
    float mu = stats[b * 64 + c], rs = stats[128 + b * 64 + c];
    float v = (y[rbase + (size_t)c * 32768 + d] - mu) * rs;
    v = (v >= 0.0f) ? v : 0.01f * v;
    v += xin[rbase + (size_t)c * 32768 + d];
    x1[rbase + (size_t)c * 32768 + d] = v;
    lds[c * 33 + d] = v;
  }
  __syncthreads();
  const size_t wbase = (size_t)b * 2515456 + (size_t)(h + 1) * 73984 + (w + 1) * 2176 + 64;
  #pragma unroll
  for (int r = 0; r < 8; r++){
    int d = r * 4 + (t >> 6), c = t & 63;
    xpad[wbase + d * 64 + c] = __float2bfloat16(lds[c * 33 + d]);
  }
}

// ---------------------------------------------------------------------------
// Fused: InstanceNorm-apply + LeakyReLU + residual + LayerNorm over C
// -> bf16 channels-last lnx [pos][64]. x2 never materialized.
// ---------------------------------------------------------------------------
__global__ __launch_bounds__(256) void apply_ln_k(const float* __restrict__ x1,
    const float* __restrict__ y, const float* __restrict__ stats,
    const float* __restrict__ lnw, const float* __restrict__ lnb,
    __hip_bfloat16* __restrict__ lnx)
{
  __shared__ float lds[64 * 33];
  __shared__ float s_mu[32], s_rs[32];
  const int t = threadIdx.x, blk = blockIdx.x;
  const int b = blk >> 10, h = (blk >> 5) & 31, w = blk & 31;
  const size_t rbase = ((size_t)(b * 64) << 15) + h * 1024 + w * 32;
  #pragma unroll
  for (int r = 0; r < 8; r++){
    int c = r * 8 + (t >> 5), d = t & 31;
    float mu = stats[b * 64 + c], rs = stats[128 + b * 64 + c];
    float v = (y[rbase + (size_t)c * 32768 + d] - mu) * rs;
    v = (v >= 0.0f) ? v : 0.01f * v;
    lds[c * 33 + d] = v + x1[rbase + (size_t)c * 32768 + d];
  }
  __syncthreads();
  if (t < 32){
    float s = 0.f, s2 = 0.f;
    for (int c = 0; c < 64; c++){ float v = lds[c * 33 + t]; s += v; s2 += v * v; }
    float mu = s * (1.f / 64.f);
    float var = s2 * (1.f / 64.f) - mu * mu;
    s_mu[t] = mu; s_rs[t] = rsqrtf(var + 1e-5f);
  }
  __syncthreads();
  const int d = t >> 3, c0 = (t & 7) * 8;
  const int pos = b * 32768 + h * 1024 + w * 32 + d;
  const float mu = s_mu[d], rs = s_rs[d];
  short8 o;
  #pragma unroll
  for (int j = 0; j < 8; j++){
    int c = c0 + j;
    o[j] = f2b((lds[c * 33 + d] - mu) * rs * lnw[c] + lnb[c]);
  }
  *(short8*)&lnx[(size_t)pos * 64 + c0] = o;
}

// ---------------------------------------------------------------------------
// GEMM [65536,64] x [64,256] -> Lbuf (cols 0-127 raw) + Gbuf (silu, 128-255).
// ---------------------------------------------------------------------------
__global__ __launch_bounds__(256) void gemm_lr_k(const __hip_bfloat16* __restrict__ lnx,
    const __hip_bfloat16* __restrict__ Wlr, __hip_bfloat16* __restrict__ Lb,
    __hip_bfloat16* __restrict__ Gb)
{
  const int t = threadIdx.x, wave = t >> 6, lane = t & 63, quad = lane >> 4, ln = lane & 15;
  const int pos0 = blockIdx.x * 64 + wave * 16;
  f32x4 acc[16];
  #pragma unroll
  for (int nt = 0; nt < 16; nt++) acc[nt] = (f32x4){0.f, 0.f, 0.f, 0.f};
  #pragma unroll
  for (int ks = 0; ks < 2; ks++){
    short8 a = *(const short8*)&lnx[(size_t)(pos0 + ln) * 64 + ks * 32 + quad * 8];
    #pragma unroll
    for (int nt = 0; nt < 16; nt++){
      short8 bv = *(const short8*)&Wlr[(nt * 16 + ln) * 64 + ks * 32 + quad * 8];
      acc[nt] = __builtin_amdgcn_mfma_f32_16x16x32_bf16(a, bv, acc[nt], 0, 0, 0);
    }
  }
  #pragma unroll
  for (int nt = 0; nt < 16; nt++){
    int col = nt * 16 + ln;
    #pragma unroll
    for (int reg = 0; reg < 4; reg++){
      int pos = pos0 + quad * 4 + reg;
      float v = acc[nt][reg];
      if (col < 128) Lb[(size_t)pos * 128 + col] = __float2bfloat16(v);
      else           Gb[(size_t)pos * 128 + col - 128] = __float2bfloat16(siluf(v));
    }
  }
}

// ---------------------------------------------------------------------------
// FUSED per-axis: conv1d(k=4)+silu -> LDS tile -> GEMM [64,128]x[128,160].
// R9: conv weights hoisted out of r-loop (c0 invariant: 256 % 16 == 0).
// ---------------------------------------------------------------------------
__global__ __launch_bounds__(256) void dbc_k(const __hip_bfloat16* __restrict__ Lb,
    const float* __restrict__ cw, const float* __restrict__ cb,
    const __hip_bfloat16* __restrict__ Wd, const float* __restrict__ db,
    __hip_bfloat16* __restrict__ xl, __hip_bfloat16* __restrict__ dbc, int sh)
{
  __shared__ short s_xl[64 * 136];
  const int t = threadIdx.x;
  const int pos0 = blockIdx.x * 64;
  const int sigma = 1 << sh;

  const int c0 = (t & 15) * 8;
  const int pibase = t >> 4;
  float4 w4[8]; float cbv[8];
  #pragma unroll
  for (int c = 0; c < 8; c++){ w4[c] = *(const float4*)&cw[(c0 + c) * 4]; cbv[c] = cb[c0 + c]; }

  #pragma unroll
  for (int r = 0; r < 4; r++){
    int pi = pibase + r * 16;
    int pos = pos0 + pi;
    int l = (pos >> sh) & 31;
    float acc[8];
    #pragma unroll
    for (int c = 0; c < 8; c++) acc[c] = cbv[c];
    #pragma unroll
    for (int j = 0; j < 4; j++){
      int off = 3 - j;
      if (l >= off){
        short8 lv = *(const short8*)&Lb[(size_t)(pos - off * sigma) * 128 + c0];
        #pragma unroll
        for (int c = 0; c < 8; c++){
          float wv = (j == 0) ? w4[c].x : (j == 1) ? w4[c].y : (j == 2) ? w4[c].z : w4[c].w;
          acc[c] += wv * b2f(lv[c]);
        }
      }
    }
    short8 o;
    #pragma unroll
    for (int c = 0; c < 8; c++) o[c] = f2b(siluf(acc[c]));
    *(short8*)&s_xl[pi * 136 + c0] = o;
    *(short8*)&xl[(size_t)pos * 128 + c0] = o;
  }
  __syncthreads();

  const int wave = t >> 6, lane = t & 63, quad = lane >> 4, ln = lane & 15;
  const int rowb = (wave * 16 + ln) * 136;
  f32x4 acc2[10];
  #pragma unroll
  for (int nt = 0; nt < 10; nt++) acc2[nt] = (f32x4){0.f, 0.f, 0.f, 0.f};
  #pragma unroll
  for (int ks = 0; ks < 4; ks++){
    short8 a = *(const short8*)&s_xl[rowb + ks * 32 + quad * 8];
    #pragma unroll
    for (int nt = 0; nt < 10; nt++){
      short8 bv = *(const short8*)&Wd[(nt * 16 + ln) * 128 + ks * 32 + quad * 8];
      acc2[nt] = __builtin_amdgcn_mfma_f32_16x16x32_bf16(a, bv, acc2[nt], 0, 0, 0);
    }
  }
  const int posw = pos0 + wave * 16 + quad * 4;
  #pragma unroll
  for (int nt = 0; nt < 10; nt++){
    int col = nt * 16 + ln;
    bool isd = col < 128;
    float dbv = isd ? db[col] : 0.f;
    #pragma unroll
    for (int reg = 0; reg < 4; reg++){
      float v = acc2[nt][reg];
      if (isd) v = fminf(fmaxf(softplusf(v + dbv), 1e-4f), 10.f);
      dbc[(size_t)(posw + reg) * 160 + col] = __float2bfloat16(v);
    }
  }
}

// ---------------------------------------------------------------------------
// Per-axis selective scan + gate + post-LN -> Ybuf (pos-major, coalesced).
// R9: bf16 y-staging (LDS 21->14KB), parallel post-LN stats, short8 B/C
// staging, precomputed negA2 + exp2f. 1 block (128 thr) per sequence.
// ---------------------------------------------------------------------------
__global__ __launch_bounds__(128) void scan_k(const __hip_bfloat16* __restrict__ dbc,
    const __hip_bfloat16* __restrict__ xl, const __hip_bfloat16* __restrict__ Gb,
    const float* __restrict__ negA2, const float* __restrict__ pnw,
    const float* __restrict__ pnb, __hip_bfloat16* __restrict__ Yb, int axis)
{
  __shared__ float s_B[512], s_C[512];
  __shared__ short s_yb[32 * 136];
  __shared__ float s_part[256];
  __shared__ float s_mu[32], s_rs[32];
  const int t = threadIdx.x, seq = blockIdx.x;
  const int b = seq >> 10, r1 = (seq >> 5) & 31, r0 = seq & 31;
  int base, sigma;
  if (axis == 0){      base = b * 32768 + r1 * 32 + r0;        sigma = 1024; }
  else if (axis == 1){ base = b * 32768 + r1 * 1024 + r0;      sigma = 32; }
  else {               base = b * 32768 + r1 * 1024 + r0 * 32; sigma = 1; }

  // B/C staging: one short8 per thread (32 rows x 4 chunks = 128 threads)
  {
    int row = t >> 2, ch = t & 3;
    short8 v = *(const short8*)&dbc[(size_t)(base + row * sigma) * 160 + 128 + ch * 8];
    float* dst = (ch < 2) ? &s_B[row * 16 + (ch & 1) * 8] : &s_C[row * 16 + (ch & 1) * 8];
    #pragma unroll
    for (int j = 0; j < 8; j++) dst[j] = b2f(v[j]);
  }
  float A2[16], h[16];
  #pragma unroll
  for (int s = 0; s < 16; s++){ A2[s] = negA2[s]; h[s] = 0.f; }
  __syncthreads();

  const int d = t;
  for (int l = 0; l < 32; l++){
    size_t row = (size_t)(base + l * sigma);
    float dt = __bfloat162float(dbc[row * 160 + d]);
    float xt = __bfloat162float(xl[row * 128 + d]);
    float g  = __bfloat162float(Gb[row * 128 + d]);
    float dx = dt * xt, yv = 0.f;
    #pragma unroll
    for (int s = 0; s < 16; s++){
      h[s] = exp2f(dt * A2[s]) * h[s] + dx * s_B[l * 16 + s];
      yv += h[s] * s_C[l * 16 + s];
    }
    s_yb[l * 136 + d] = f2b(yv * g);
  }
  __syncthreads();
  // parallel post-LN stats: thread (l = t&31, grp = t>>5) sums a 32-d chunk
  {
    int lq = t & 31, grp = t >> 5;
    const short* row = &s_yb[lq * 136 + grp * 32];
    float s = 0.f, s2 = 0.f;
    #pragma unroll 8
    for (int k = 0; k < 32; k++){ float v = b2f(row[k]); s += v; s2 += v * v; }
    s_part[(lq * 4 + grp) * 2]     = s;
    s_part[(lq * 4 + grp) * 2 + 1] = s2;
  }
  __syncthreads();
  if (t < 32){
    float s  = s_part[t * 8]     + s_part[t * 8 + 2] + s_part[t * 8 + 4] + s_part[t * 8 + 6];
    float s2 = s_part[t * 8 + 1] + s_part[t * 8 + 3] + s_part[t * 8 + 5] + s_part[t * 8 + 7];
    float mu = s * (1.f / 128.f), var = s2 * (1.f / 128.f) - mu * mu;
    s_mu[t] = mu; s_rs[t] = rsqrtf(fmaxf(var, 0.f) + 1e-5f);
  }
  __syncthreads();
  const float pw = pnw[d], pb = pnb[d];
  for (int l = 0; l < 32; l++){
    float v = (b2f(s_yb[l * 136 + d]) - s_mu[l]) * s_rs[l] * pw + pb;
    Yb[(size_t)(base + l * sigma) * 128 + d] = __float2bfloat16(v);
  }
}

// ---------------------------------------------------------------------------
// GEMM out + weighted accumulate into d_out (pos-ordered -> coalesced).
// mode: 0=first (store), 1=middle (add), 2=last (add + residual finalize).
// ---------------------------------------------------------------------------
__global__ __launch_bounds__(256) void gemm_out_k(const __hip_bfloat16* __restrict__ Yb,
    const __hip_bfloat16* __restrict__ oW, const float* __restrict__ axw,
    const float* __restrict__ xres, const float* __restrict__ rsc,
    float* __restrict__ outp, int axis, int mode)
{
  const int t = threadIdx.x, wave = t >> 6, lane = t & 63, quad = lane >> 4, ln = lane & 15;
  const int pos0 = blockIdx.x * 64 + wave * 16;
  f32x4 acc[4];
  #pragma unroll
  for (int mt = 0; mt < 4; mt++) acc[mt] = (f32x4){0.f, 0.f, 0.f, 0.f};
  #pragma unroll
  for (int ks = 0; ks < 4; ks++){
    short8 bv = *(const short8*)&Yb[(size_t)(pos0 + ln) * 128 + ks * 32 + quad * 8];
    #pragma unroll
    for (int mt = 0; mt < 4; mt++){
      short8 a = *(const short8*)&oW[(mt * 16 + ln) * 128 + ks * 32 + quad * 8];
      acc[mt] = __builtin_amdgcn_mfma_f32_16x16x32_bf16(a, bv, acc[mt], 0, 0, 0);
    }
  }
  float a0 = axw[0], a1 = axw[1], a2 = axw[2];
  float mx = fmaxf(a0, fmaxf(a1, a2));
  float e0 = __expf(a0 - mx), e1 = __expf(a1 - mx), e2 = __expf(a2 - mx);
  float wax = ((axis == 0) ? e0 : (axis == 1) ? e1 : e2) / (e0 + e1 + e2);
  float rs = rsc[0];
  const int pos = pos0 + ln;
  const int bb = pos >> 15, hwd = pos & 32767;
  #pragma unroll
  for (int mt = 0; mt < 4; mt++){
    #pragma unroll
    for (int reg = 0; reg < 4; reg++){
      int co = mt * 16 + quad * 4 + reg;
      size_t idx = (((size_t)(bb * 64 + co)) << 15) + hwd;
      float v = acc[mt][reg] * wax;
      if (mode == 0)      outp[idx] = v;
      else if (mode == 1) outp[idx] += v;
      else                outp[idx] = xres[idx] + rs * (outp[idx] + v);
    }
  }
}

// ---------------------------------------------------------------------------
extern "C" void kernel_launch(void* const* d_in, const int* in_sizes, int n_in,
                              void* d_out, int out_size, void* d_ws, size_t ws_size,
                              hipStream_t stream)
{
  const float* x      = (const float*)d_in[0];
  const float* cr1w   = (const float*)d_in[1];
  const float* cr2w   = (const float*)d_in[3];
  const float* ln_w   = (const float*)d_in[5];
  const float* ln_b   = (const float*)d_in[6];
  const float* left_w = (const float*)d_in[7];
  const float* c1dw   = (const float*)d_in[8];
  const float* c1db   = (const float*)d_in[9];
  const float* dw     = (const float*)d_in[10];
  const float* db     = (const float*)d_in[11];
  const float* bpw    = (const float*)d_in[12];
  const float* cpw    = (const float*)d_in[13];
  const float* alog   = (const float*)d_in[14];
  const float* rw     = (const float*)d_in[15];
  const float* pnw    = (const float*)d_in[16];
  const float* pnb    = (const float*)d_in[17];
  const float* ow     = (const float*)d_in[18];
  const float* rsc    = (const float*)d_in[19];
  const float* axw    = (const float*)d_in[20];
  float* out = (float*)d_out;                       // conv raw out, then mamba accum
  float* wsf = (float*)d_ws;

  float* buf1   = wsf;                                         // x1 fp32; later xl bf16 alias
  float* stats  = wsf + 4194304;                               // 256 f
  float* negA2  = wsf + 4194560;                               // 16 f (gap region)
  __hip_bfloat16* W4a  = (__hip_bfloat16*)(wsf + 4194816);     // 110,592 bf16
  __hip_bfloat16* W4b  = W4a + 110592;
  __hip_bfloat16* Wlr  = (__hip_bfloat16*)(wsf + 4305408);     // 16,384 bf16
  __hip_bfloat16* Wdbc = (__hip_bfloat16*)(wsf + 4313600);     // 20,480 bf16
  __hip_bfloat16* oWp  = (__hip_bfloat16*)(wsf + 4323840);     // 8,192 bf16
  __hip_bfloat16* xpad = (__hip_bfloat16*)(wsf + 4327936);     // 5,030,912 bf16
  __hip_bfloat16* lnx  = xpad;                                 // alias (post-conv)
  __hip_bfloat16* Lbuf = (__hip_bfloat16*)(wsf + 6843392);     // 8,388,608 bf16
  __hip_bfloat16* Gbuf = (__hip_bfloat16*)(wsf + 11037696);    // 8,388,608 bf16
  __hip_bfloat16* dbc  = (__hip_bfloat16*)(wsf + 15232000);    // 10,485,760 bf16
  __hip_bfloat16* Ybuf = (__hip_bfloat16*)(wsf + 20474880);    // 8,388,608 bf16
  __hip_bfloat16* xl   = (__hip_bfloat16*)buf1;                // alias (x1 dead after apply_ln)

  setup_k<<<3497, 256, 0, stream>>>((uint4*)xpad, cr1w, cr2w, left_w, rw, dw, bpw, cpw, ow,
                                    alog, W4a, W4b, Wlr, Wdbc, oWp, negA2);

  // conv-res block 1
  pack_k<<<2048, 256, 0, stream>>>(x, xpad);
  conv_mfma_k<<<512, 256, 0, stream>>>(xpad, W4a, out);
  inorm_stats_k<<<128, 256, 0, stream>>>(out, stats);
  apply_pack_k<<<2048, 256, 0, stream>>>(x, out, stats, buf1, xpad);
  // conv-res block 2 (fused apply + LayerNorm; x2 never materialized)
  conv_mfma_k<<<512, 256, 0, stream>>>(xpad, W4b, out);
  inorm_stats_k<<<128, 256, 0, stream>>>(out, stats);
  apply_ln_k<<<2048, 256, 0, stream>>>(buf1, out, stats, ln_w, ln_b, lnx);

  // mamba: axis-independent projection once
  gemm_lr_k<<<1024, 256, 0, stream>>>(lnx, Wlr, Lbuf, Gbuf);

  // per-axis: dbc_k (conv1d+gemm fused) -> scan_k -> gemm_out_k (coalesced)
  const int sh[3] = {10, 5, 0};
  for (int axis = 0; axis < 3; axis++){
    dbc_k<<<1024, 256, 0, stream>>>(Lbuf, c1dw, c1db, Wdbc, db, xl, dbc, sh[axis]);
    scan_k<<<2048, 128, 0, stream>>>(dbc, xl, Gbuf, negA2, pnw, pnb, Ybuf, axis);
    gemm_out_k<<<1024, 256, 0, stream>>>(Ybuf, oWp, axw, x, rsc, out, axis,
                                         axis == 0 ? 0 : (axis == 2 ? 2 : 1));
  }
}